// Round 3
// baseline (538.472 us; speedup 1.0000x reference)
//
#include <hip/hip_runtime.h>

constexpr int NN  = 50000;   // nodes
constexpr int NE  = 800000;  // edges

using frag_ab = __attribute__((ext_vector_type(8))) short;     // 8 bf16
using frag_h  = __attribute__((ext_vector_type(8))) _Float16;  // 8 fp16
using frag_cd = __attribute__((ext_vector_type(4))) float;     // 4 fp32
using h2      = __attribute__((ext_vector_type(2))) _Float16;  // 2 fp16

__device__ __forceinline__ unsigned short f2bf(float f) {   // RNE
    union { float f; unsigned u; } v; v.f = f;
    unsigned r = v.u + 0x7FFFu + ((v.u >> 16) & 1u);
    return (unsigned short)(r >> 16);
}
__device__ __forceinline__ unsigned short f2h(float f) {    // RNE via HW cvt
    union { _Float16 h; unsigned short u; } v; v.h = (_Float16)f; return v.u;
}
__device__ __forceinline__ float bflo(unsigned u) {
    union { unsigned u; float f; } v; v.u = u << 16; return v.f;
}
__device__ __forceinline__ float bfhi(unsigned u) {
    union { unsigned u; float f; } v; v.u = u & 0xFFFF0000u; return v.f;
}
__device__ __forceinline__ float bfs(unsigned short u) {
    union { unsigned u; float f; } v; v.u = (unsigned)u << 16; return v.f;
}
__device__ __forceinline__ unsigned packbf(float a, float b) {       // RNE
    return (unsigned)f2bf(a) | ((unsigned)f2bf(b) << 16);
}
// packed fp16 relu(a+b): clang lowers to v_pk_add_f16 + v_pk_max_f16 (2 VALU ops)
__device__ __forceinline__ unsigned pk_add_relu(unsigned a, unsigned b) {
    union Cu { unsigned u; h2 h; };
    Cu ua; ua.u = a;
    Cu ub; ub.u = b;
    h2 s = ua.h + ub.h;
    h2 z; z[0] = (_Float16)0.f; z[1] = (_Float16)0.f;
    Cu r; r.h = __builtin_elementwise_max(s, z);
    return r.u;
}

enum { EPI_LAYER = 1, EPI_PQBF = 2, EPI_PQH = 3 };

// ---------------------------------------------------------------------------
// MFMA bf16 GEMM. Block: 64 rows x 128 cols, 4 waves, BK=64.
// EPI_PQH writes fp16 output (feeds the fp16 edge pipeline).
// ---------------------------------------------------------------------------
template<int EPI>
__launch_bounds__(256, 4)
__global__ void mfma_gemm_k(const unsigned short* __restrict__ A0,
                            const unsigned short* __restrict__ A1,
                            int lda, int kSplit,
                            const unsigned short* __restrict__ Wt,
                            const float* __restrict__ bias,
                            unsigned short* __restrict__ Cbf, int ldc,
                            const unsigned short* __restrict__ residbf,
                            int M, int K)
{
    __shared__ __align__(16) unsigned short As[64][72];    // [row][k], pad 8
    __shared__ __align__(16) unsigned short Ws[128][72];   // [n][k],  pad 8
    __shared__ float bs[128];
    __shared__ float part[(EPI == EPI_LAYER) ? 64 : 1][17];
    __shared__ float rinv[(EPI == EPI_LAYER) ? 64 : 1];

    const int t  = threadIdx.x;
    const int by = blockIdx.y;
    Wt   += (size_t)by * 128 * K;
    bias += (size_t)by * 128;
    if constexpr (EPI != EPI_LAYER) Cbf += (size_t)by * 128;
    const int m0 = blockIdx.x * 64;

    if (t < 128) bs[t] = bias[t];

    const int wv = t >> 6, l = t & 63, lq = l >> 4, lm = l & 15;
    frag_cd acc[8];
#pragma unroll
    for (int tb = 0; tb < 8; ++tb) acc[tb] = (frag_cd){0.f, 0.f, 0.f, 0.f};

    for (int kt = 0; kt < K; kt += 64) {
        const unsigned short* Asrc = (kt < kSplit) ? A0 : A1;
        const int kcol = (kt < kSplit) ? kt : kt - kSplit;
#pragma unroll
        for (int p = 0; p < 2; ++p) {
            int idx = p * 256 + t;            // 512 uint4 = 64 x 64 bf16
            int row = idx >> 3, c4 = idx & 7;
            int gm = m0 + row;
            uint4 v = make_uint4(0, 0, 0, 0);
            if (gm < M) v = *(const uint4*)&Asrc[(size_t)gm * lda + kcol + c4 * 8];
            *(uint4*)&As[row][c4 * 8] = v;
        }
#pragma unroll
        for (int p = 0; p < 4; ++p) {
            int idx = p * 256 + t;            // 1024 uint4 = 128 x 64 bf16
            int n = idx >> 3, c4 = idx & 7;
            *(uint4*)&Ws[n][c4 * 8] = *(const uint4*)&Wt[(size_t)n * K + kt + c4 * 8];
        }
        __syncthreads();
#pragma unroll
        for (int kb = 0; kb < 2; ++kb) {
            frag_ab af = *(const frag_ab*)&As[wv * 16 + lm][kb * 32 + lq * 8];
#pragma unroll
            for (int tb = 0; tb < 8; ++tb) {
                frag_ab bf = *(const frag_ab*)&Ws[tb * 16 + lm][kb * 32 + lq * 8];
                acc[tb] = __builtin_amdgcn_mfma_f32_16x16x32_bf16(af, bf, acc[tb], 0, 0, 0);
            }
        }
        __syncthreads();
    }

    if constexpr (EPI == EPI_LAYER) {
        float sq[4] = {0.f, 0.f, 0.f, 0.f};
#pragma unroll
        for (int tb = 0; tb < 8; ++tb) {
            float b = bs[tb * 16 + lm];
#pragma unroll
            for (int r = 0; r < 4; ++r) {
                acc[tb][r] += b;
                sq[r] += acc[tb][r] * acc[tb][r];
            }
        }
#pragma unroll
        for (int r = 0; r < 4; ++r) part[wv * 16 + lq * 4 + r][lm] = sq[r];
        __syncthreads();
        if (t < 64) {
            float s = 0.f;
#pragma unroll
            for (int c = 0; c < 16; ++c) s += part[t][c];
            rinv[t] = 1.0f / fmaxf(sqrtf(s), 1e-12f);
        }
        __syncthreads();
#pragma unroll
        for (int r = 0; r < 4; ++r) {
            int gr = m0 + wv * 16 + lq * 4 + r;
            if (gr >= M) continue;
            float ri = rinv[wv * 16 + lq * 4 + r];
#pragma unroll
            for (int tb = 0; tb < 8; ++tb) {
                int col = tb * 16 + lm;
                float o = bfs(residbf[(size_t)gr * 128 + col]) +
                          fmaxf(acc[tb][r], 0.f) * ri;
                Cbf[(size_t)gr * 128 + col] = f2bf(o);
            }
        }
    } else {
#pragma unroll
        for (int r = 0; r < 4; ++r) {
            int gr = m0 + wv * 16 + lq * 4 + r;
            if (gr >= M) continue;
#pragma unroll
            for (int tb = 0; tb < 8; ++tb) {
                int col = tb * 16 + lm;
                float v = acc[tb][r] + bs[col];
                Cbf[(size_t)gr * ldc + col] =
                    (EPI == EPI_PQH) ? f2h(v) : f2bf(v);
            }
        }
    }
}

// ---------------------------------------------------------------------------
// x -> bf16 cast (embed input)
// ---------------------------------------------------------------------------
__global__ void cast_k(const float* __restrict__ x, unsigned short* __restrict__ xbf,
                       int n8) {
    int i = blockIdx.x * 256 + threadIdx.x;
    if (i >= n8) return;
    float4 a = *(const float4*)&x[(size_t)i * 8];
    float4 b = *(const float4*)&x[(size_t)i * 8 + 4];
    uint4 o = make_uint4(packbf(a.x, a.y), packbf(a.z, a.w),
                         packbf(b.x, b.y), packbf(b.z, b.w));
    *(uint4*)&xbf[(size_t)i * 8] = o;
}

// ---------------------------------------------------------------------------
// CSR construction -> packed pk[pos]={src,dst,eid,0} + compact srt[pos]=src
// ---------------------------------------------------------------------------
__global__ void deg_k(const int* __restrict__ dst, int* __restrict__ deg) {
    int e = blockIdx.x * 256 + threadIdx.x;
    if (e < NE) atomicAdd(&deg[dst[e]], 1);
}

__global__ void scan1_k(const int* __restrict__ deg, int* __restrict__ rp,
                        int* __restrict__ bsum) {
    __shared__ int sh[512];
    int tid = threadIdx.x;
    int i = blockIdx.x * 512 + tid;
    int v = (i < NN) ? deg[i] : 0;
    sh[tid] = v;
    __syncthreads();
    for (int ofs = 1; ofs < 512; ofs <<= 1) {
        int x = (tid >= ofs) ? sh[tid - ofs] : 0;
        __syncthreads();
        sh[tid] += x;
        __syncthreads();
    }
    if (i < NN) rp[i] = sh[tid] - v;
    if (tid == 511) bsum[blockIdx.x] = sh[511];
}

__global__ void scan2_k(int* __restrict__ bsum, int nb) {
    __shared__ int sh[128];
    int tid = threadIdx.x;
    int v = (tid < nb) ? bsum[tid] : 0;
    sh[tid] = v;
    __syncthreads();
    for (int ofs = 1; ofs < 128; ofs <<= 1) {
        int x = (tid >= ofs) ? sh[tid - ofs] : 0;
        __syncthreads();
        sh[tid] += x;
        __syncthreads();
    }
    if (tid < nb) bsum[tid] = sh[tid] - v;
}

__global__ void scan3_k(int* __restrict__ rp, const int* __restrict__ bsum,
                        const int* __restrict__ deg, float* __restrict__ invd) {
    int i = blockIdx.x * 512 + threadIdx.x;
    if (i < NN) {
        rp[i] += bsum[blockIdx.x];
        int d = deg[i];
        invd[i] = 1.0f / (float)(d > 1 ? d : 1);
    }
    if (i == NN) rp[NN] = NE;
}

__global__ void fill_k(const int* __restrict__ src, const int* __restrict__ dst,
                       const int* __restrict__ rp, int* __restrict__ cnt,
                       int4* __restrict__ pk, int* __restrict__ srt) {
    int e = blockIdx.x * 256 + threadIdx.x;
    if (e < NE) {
        int s = src[e];
        int d = dst[e];
        int pos = rp[d] + atomicAdd(&cnt[d], 1);
        pk[pos]  = make_int4(s, d, e, 0);
        srt[pos] = s;
    }
}

// ---------------------------------------------------------------------------
// Mean aggregation, one WAVE per node. Lane layout: 32 lanes x 8 B per row,
// wave halves process alternating neighbor rows => 1 VMEM instr / 2 rows,
// 4-pair unroll => 8 rows in flight. Halves combined via shfl_xor(32).
// ---------------------------------------------------------------------------
__launch_bounds__(256, 8)
__global__ void agg_k(const unsigned short* __restrict__ hbf,
                      const int* __restrict__ rp, const int* __restrict__ srt,
                      const float* __restrict__ invd,
                      unsigned short* __restrict__ cbf) {
    int gw   = (blockIdx.x * 256 + threadIdx.x) >> 6;   // node = global wave id
    if (gw >= NN) return;
    const int lane = threadIdx.x & 63;
    const int half = lane >> 5;          // which neighbor of the pair
    const int hl   = lane & 31;          // feature group: 4 feats (8 B)
    const int b = rp[gw], e = rp[gw + 1];
    float a0 = 0.f, a1 = 0.f, a2 = 0.f, a3 = 0.f;

    int p = b;
    for (; p + 8 <= e; p += 8) {         // 4 pairs, 8 rows in flight
        int s0 = srt[p     + half];
        int s1 = srt[p + 2 + half];
        int s2 = srt[p + 4 + half];
        int s3 = srt[p + 6 + half];
        uint2 u0 = *(const uint2*)&hbf[(size_t)s0 * 128 + hl * 4];
        uint2 u1 = *(const uint2*)&hbf[(size_t)s1 * 128 + hl * 4];
        uint2 u2 = *(const uint2*)&hbf[(size_t)s2 * 128 + hl * 4];
        uint2 u3 = *(const uint2*)&hbf[(size_t)s3 * 128 + hl * 4];
        a0 += bflo(u0.x) + bflo(u1.x) + bflo(u2.x) + bflo(u3.x);
        a1 += bfhi(u0.x) + bfhi(u1.x) + bfhi(u2.x) + bfhi(u3.x);
        a2 += bflo(u0.y) + bflo(u1.y) + bflo(u2.y) + bflo(u3.y);
        a3 += bfhi(u0.y) + bfhi(u1.y) + bfhi(u2.y) + bfhi(u3.y);
    }
    for (; p + 2 <= e; p += 2) {         // single pair
        int s = srt[p + half];
        uint2 u = *(const uint2*)&hbf[(size_t)s * 128 + hl * 4];
        a0 += bflo(u.x); a1 += bfhi(u.x);
        a2 += bflo(u.y); a3 += bfhi(u.y);
    }
    if (p < e && half == 0) {            // odd-degree tail (half 0 only)
        int s = srt[p];
        uint2 u = *(const uint2*)&hbf[(size_t)s * 128 + hl * 4];
        a0 += bflo(u.x); a1 += bfhi(u.x);
        a2 += bflo(u.y); a3 += bfhi(u.y);
    }
    // combine halves
    a0 += __shfl_xor(a0, 32, 64);
    a1 += __shfl_xor(a1, 32, 64);
    a2 += __shfl_xor(a2, 32, 64);
    a3 += __shfl_xor(a3, 32, 64);

    float iv = invd[gw];
    if (half == 0) {
        uint2 r = make_uint2(packbf(a0 * iv, a1 * iv), packbf(a2 * iv, a3 * iv));
        *(uint2*)&cbf[(size_t)gw * 128 + hl * 4] = r;
    }
}

// ---------------------------------------------------------------------------
// Prep: Wct[4][128n][256k] bf16; Wefft[256n][128k] bf16; W1tg[64n][128k] FP16;
// beff; Wembt bf16.
// ---------------------------------------------------------------------------
__global__ void prep_k(const float* __restrict__ Wconv, const float* __restrict__ W0,
                       const float* __restrict__ b0, const float* __restrict__ W1,
                       const float* __restrict__ Wemb,
                       unsigned short* __restrict__ Wct,
                       unsigned short* __restrict__ Wefft,
                       float* __restrict__ beff, unsigned short* __restrict__ W1tg,
                       unsigned short* __restrict__ Wembt) {
    int i = blockIdx.x * 256 + threadIdx.x;
    if (i < 131072) {
        int lyr = i >> 15, r = i & 32767, n = r >> 8, k = r & 255;
        Wct[i] = f2bf(Wconv[(size_t)lyr * 32768 + k * 128 + n]);
    } else if (i < 163840) {
        int j = i - 131072, n = j >> 7, k = j & 127;
        float v = (n < 128) ? W0[k * 128 + n] : W0[(128 + k) * 128 + (n - 128)];
        Wefft[j] = f2bf(v);
    } else if (i < 172032) {
        int j = i - 163840, n = j >> 7, k = j & 127;
        W1tg[j] = f2h(W1[k * 64 + n]);                 // fp16 for edge MFMA
    } else if (i < 172288) {
        int j = i - 172032;
        beff[j] = (j < 128) ? b0[j] : 0.f;
    } else if (i < 180480) {
        int j = i - 172288, n = j >> 6, k = j & 63;
        Wembt[j] = f2bf(Wemb[k * 128 + n]);
    }
}

// ---------------------------------------------------------------------------
// Fused edge readout (fp16 MFMA), ZERO-LDS / ZERO-BARRIER version.
// 64 edges/block, 256 threads (4 waves x 16 edges).
// Each lane gathers exactly its own MFMA A-fragment slices of p[src]/q[dst]
// (lane (lq,lm) holds A-row lm, k = kb*32+lq*8): 8 independent 16B gathers,
// relu(p+q) via packed fp16 in-register -> af frags directly in-lane.
// B-fragments read straight from the 16KB W1tg table (L1-resident).
// Edge-id for output row obtained via width-16 shfl (lane lm holds edge
// wv*16+lm's pk entry; output row needs edge wv*16+lq*4+r).
// ---------------------------------------------------------------------------
__launch_bounds__(256)
__global__ void edge_mlp_k(const unsigned short* __restrict__ pq,   // fp16 [NN][256]
                           const int4* __restrict__ pk,
                           const unsigned short* __restrict__ W1tg, // fp16 [64][128]
                           const float* __restrict__ b1,
                           const float* __restrict__ W2, const float* __restrict__ b2,
                           float* __restrict__ out)
{
    const int t  = threadIdx.x;
    const int wv = t >> 6, l = t & 63, lq = l >> 4, lm = l & 15;
    const int p0 = blockIdx.x * 64;          // 64 edges per block
    const int erow = wv * 16 + lm;           // this lane's edge (A-row)

    int4 pkv = pk[p0 + erow];
    const unsigned short* pr = pq + (size_t)pkv.x * 256 + lq * 8;
    const unsigned short* qr = pq + (size_t)pkv.y * 256 + 128 + lq * 8;

    // 8 independent 16B gathers (all in flight before first use)
    uint4 pa[4], qa[4];
#pragma unroll
    for (int kb = 0; kb < 4; ++kb) pa[kb] = *(const uint4*)(pr + kb * 32);
#pragma unroll
    for (int kb = 0; kb < 4; ++kb) qa[kb] = *(const uint4*)(qr + kb * 32);

    // af[kb] = relu(p+q) packed fp16, already in MFMA A-fragment layout
    frag_h af[4];
#pragma unroll
    for (int kb = 0; kb < 4; ++kb) {
        union { uint4 u; frag_h h; } cv;
        cv.u = make_uint4(pk_add_relu(pa[kb].x, qa[kb].x),
                          pk_add_relu(pa[kb].y, qa[kb].y),
                          pk_add_relu(pa[kb].z, qa[kb].z),
                          pk_add_relu(pa[kb].w, qa[kb].w));
        af[kb] = cv.h;
    }

    // MFMA: B-fragments direct from global W1tg (16KB, L1-resident)
    frag_cd acc[4];
#pragma unroll
    for (int tb = 0; tb < 4; ++tb) acc[tb] = (frag_cd){0.f, 0.f, 0.f, 0.f};
#pragma unroll
    for (int kb = 0; kb < 4; ++kb) {
#pragma unroll
        for (int tb = 0; tb < 4; ++tb) {
            frag_h bf = *(const frag_h*)
                &W1tg[(size_t)(tb * 16 + lm) * 128 + kb * 32 + lq * 8];
            acc[tb] = __builtin_amdgcn_mfma_f32_16x16x32_f16(af[kb], bf, acc[tb], 0, 0, 0);
        }
    }

    // in-register MLP2 (b1/W2 direct from global, L2-resident)
    float b1v[4], w20[4], w21[4];
#pragma unroll
    for (int tb = 0; tb < 4; ++tb) {
        int o = tb * 16 + lm;
        b1v[tb] = b1[o];
        w20[tb] = W2[o * 2];
        w21[tb] = W2[o * 2 + 1];
    }
    const float bo0 = b2[0], bo1 = b2[1];
#pragma unroll
    for (int r = 0; r < 4; ++r) {
        float s0 = 0.f, s1 = 0.f;
#pragma unroll
        for (int tb = 0; tb < 4; ++tb) {
            float e1 = fmaxf(acc[tb][r] + b1v[tb], 0.f);
            s0 += e1 * w20[tb];
            s1 += e1 * w21[tb];
        }
#pragma unroll
        for (int m = 1; m < 16; m <<= 1) {   // reduce over lm
            s0 += __shfl_xor(s0, m, 16);
            s1 += __shfl_xor(s1, m, 16);
        }
        int eo = __shfl(pkv.z, lq * 4 + r, 16);  // eid of output edge row
        if (lm == 0) {
            *(float2*)&out[(size_t)eo * 2] = make_float2(s0 + bo0, s1 + bo1);
        }
    }
}

// ---------------------------------------------------------------------------
extern "C" void kernel_launch(void* const* d_in, const int* in_sizes, int n_in,
                              void* d_out, int out_size, void* d_ws, size_t ws_size,
                              hipStream_t stream)
{
    const float* x    = (const float*)d_in[0];
    const int*   esrc = (const int*)  d_in[1];
    const int*   edst = (const int*)  d_in[2];
    const float* Wemb  = (const float*)d_in[5];
    const float* bemb  = (const float*)d_in[6];
    const float* Wconv = (const float*)d_in[7];
    const float* bconv = (const float*)d_in[8];
    const float* Wm0   = (const float*)d_in[9];
    const float* bm0   = (const float*)d_in[10];
    const float* Wm1   = (const float*)d_in[11];
    const float* bm1   = (const float*)d_in[12];
    const float* Wm2   = (const float*)d_in[13];
    const float* bm2   = (const float*)d_in[14];
    float* out = (float*)d_out;

    char* ws = (char*)d_ws;
    size_t off = 0;
    auto alloc = [&](size_t bytes) -> void* {
        void* p = ws + off;
        off = (off + bytes + 255) & ~(size_t)255;
        return p;
    };
    unsigned short* h0bf = (unsigned short*)alloc((size_t)NN * 128 * 2);
    unsigned short* h1bf = (unsigned short*)alloc((size_t)NN * 128 * 2);
    unsigned short* cbf  = (unsigned short*)alloc((size_t)NN * 128 * 2);
    unsigned short* pqb  = (unsigned short*)alloc((size_t)NN * 256 * 2);
    unsigned short* xbf  = (unsigned short*)alloc((size_t)NN * 64 * 2);
    unsigned short* Wct   = (unsigned short*)alloc(4 * 128 * 256 * 2);
    unsigned short* Wefft = (unsigned short*)alloc(256 * 128 * 2);
    float*          beff  = (float*)alloc(256 * 4);
    unsigned short* W1tg  = (unsigned short*)alloc(64 * 128 * 2);
    unsigned short* Wembt = (unsigned short*)alloc(128 * 64 * 2);
    int*   deg  = (int*)alloc((size_t)NN * 4);
    int*   rp   = (int*)alloc((size_t)(NN + 1) * 4);
    int*   cnt  = (int*)alloc((size_t)NN * 4);
    float* invd = (float*)alloc((size_t)NN * 4);
    int*   bsum = (int*)alloc(512);
    int4*  pk   = (int4*)alloc((size_t)NE * 16);
    int*   srt  = (int*)alloc((size_t)NE * 4);
    (void)ws_size; (void)in_sizes; (void)n_in; (void)out_size;

    hipMemsetAsync(deg, 0, (size_t)NN * 4, stream);
    hipMemsetAsync(cnt, 0, (size_t)NN * 4, stream);

    // cast x -> bf16; weight prep
    cast_k<<<(NN * 64 / 8 + 255) / 256, 256, 0, stream>>>(x, xbf, NN * 64 / 8);
    prep_k<<<(180480 + 255) / 256, 256, 0, stream>>>(
        Wconv, Wm0, bm0, Wm1, Wemb, Wct, Wefft, beff, W1tg, Wembt);

    // CSR build (packed + compact srt)
    deg_k  <<<(NE + 255) / 256, 256, 0, stream>>>(edst, deg);
    scan1_k<<<(NN + 511) / 512, 512, 0, stream>>>(deg, rp, bsum);
    scan2_k<<<1, 128, 0, stream>>>(bsum, (NN + 511) / 512);
    scan3_k<<<(NN + 511) / 512, 512, 0, stream>>>(rp, bsum, deg, invd);
    fill_k <<<(NE + 255) / 256, 256, 0, stream>>>(esrc, edst, rp, cnt, pk, srt);

    // h0 = bf16(x @ Wemb + bemb) via MFMA
    mfma_gemm_k<EPI_PQBF><<<dim3((NN + 63) / 64, 1), 256, 0, stream>>>(
        xbf, nullptr, 64, 1 << 30, Wembt, bemb, h0bf, 128, nullptr, NN, 64);

    // 4 SAGE layers (MFMA, bf16 residual)
    unsigned short* hcbf = h0bf; unsigned short* hnbf = h1bf;
    for (int l = 0; l < 4; ++l) {
        agg_k<<<(NN + 3) / 4, 256, 0, stream>>>(hcbf, rp, srt, invd, cbf);
        mfma_gemm_k<EPI_LAYER><<<dim3((NN + 63) / 64, 1), 256, 0, stream>>>(
            hcbf, cbf, 128, 128, Wct + (size_t)l * 128 * 256,
            bconv + (size_t)l * 128, hnbf, 128, hcbf, NN, 256);
        unsigned short* tb = hcbf; hcbf = hnbf; hnbf = tb;
    }
    // after 4 layers: hcbf == h0bf

    // pq = fp16(h @ Weff + beff)  [NN][256]  (fp16 feeds edge pipeline)
    mfma_gemm_k<EPI_PQH><<<dim3((NN + 63) / 64, 2), 256, 0, stream>>>(
        hcbf, nullptr, 128, 1 << 30, Wefft, beff, pqb, 256, nullptr, NN, 128);

    // fused edge readout (zero-LDS, zero-barrier, 64 edges/block)
    edge_mlp_k<<<NE / 64, 256, 0, stream>>>(pqb, pk, W1tg, bm1, Wm2, bm2, out);
}

// Round 4
// 474.726 us; speedup vs baseline: 1.1343x; 1.1343x over previous
//
#include <hip/hip_runtime.h>

constexpr int NN  = 50000;   // nodes
constexpr int NE  = 800000;  // edges

using frag_ab = __attribute__((ext_vector_type(8))) short;     // 8 bf16
using frag_h  = __attribute__((ext_vector_type(8))) _Float16;  // 8 fp16
using frag_cd = __attribute__((ext_vector_type(4))) float;     // 4 fp32
using h2      = __attribute__((ext_vector_type(2))) _Float16;  // 2 fp16

__device__ __forceinline__ unsigned short f2bf(float f) {   // RNE
    union { float f; unsigned u; } v; v.f = f;
    unsigned r = v.u + 0x7FFFu + ((v.u >> 16) & 1u);
    return (unsigned short)(r >> 16);
}
__device__ __forceinline__ unsigned short f2h(float f) {    // RNE via HW cvt
    union { _Float16 h; unsigned short u; } v; v.h = (_Float16)f; return v.u;
}
__device__ __forceinline__ float bflo(unsigned u) {
    union { unsigned u; float f; } v; v.u = u << 16; return v.f;
}
__device__ __forceinline__ float bfhi(unsigned u) {
    union { unsigned u; float f; } v; v.u = u & 0xFFFF0000u; return v.f;
}
__device__ __forceinline__ float bfs(unsigned short u) {
    union { unsigned u; float f; } v; v.u = (unsigned)u << 16; return v.f;
}
__device__ __forceinline__ unsigned packbf(float a, float b) {       // RNE
    return (unsigned)f2bf(a) | ((unsigned)f2bf(b) << 16);
}
// packed fp16 relu(a+b): clang lowers to v_pk_add_f16 + v_pk_max_f16 (2 VALU ops)
__device__ __forceinline__ unsigned pk_add_relu(unsigned a, unsigned b) {
    union Cu { unsigned u; h2 h; };
    Cu ua; ua.u = a;
    Cu ub; ub.u = b;
    h2 s = ua.h + ub.h;
    h2 z; z[0] = (_Float16)0.f; z[1] = (_Float16)0.f;
    Cu r; r.h = __builtin_elementwise_max(s, z);
    return r.u;
}

enum { EPI_LAYER = 1, EPI_PQBF = 2, EPI_PQH = 3 };

// ---------------------------------------------------------------------------
// MFMA bf16 GEMM. Block: 64 rows x 128 cols, 4 waves, BK=64.
// EPI_PQH writes fp16 output (feeds the fp16 edge pipeline).
// ---------------------------------------------------------------------------
template<int EPI>
__launch_bounds__(256, 4)
__global__ void mfma_gemm_k(const unsigned short* __restrict__ A0,
                            const unsigned short* __restrict__ A1,
                            int lda, int kSplit,
                            const unsigned short* __restrict__ Wt,
                            const float* __restrict__ bias,
                            unsigned short* __restrict__ Cbf, int ldc,
                            const unsigned short* __restrict__ residbf,
                            int M, int K)
{
    __shared__ __align__(16) unsigned short As[64][72];    // [row][k], pad 8
    __shared__ __align__(16) unsigned short Ws[128][72];   // [n][k],  pad 8
    __shared__ float bs[128];
    __shared__ float part[(EPI == EPI_LAYER) ? 64 : 1][17];
    __shared__ float rinv[(EPI == EPI_LAYER) ? 64 : 1];

    const int t  = threadIdx.x;
    const int by = blockIdx.y;
    Wt   += (size_t)by * 128 * K;
    bias += (size_t)by * 128;
    if constexpr (EPI != EPI_LAYER) Cbf += (size_t)by * 128;
    const int m0 = blockIdx.x * 64;

    if (t < 128) bs[t] = bias[t];

    const int wv = t >> 6, l = t & 63, lq = l >> 4, lm = l & 15;
    frag_cd acc[8];
#pragma unroll
    for (int tb = 0; tb < 8; ++tb) acc[tb] = (frag_cd){0.f, 0.f, 0.f, 0.f};

    for (int kt = 0; kt < K; kt += 64) {
        const unsigned short* Asrc = (kt < kSplit) ? A0 : A1;
        const int kcol = (kt < kSplit) ? kt : kt - kSplit;
#pragma unroll
        for (int p = 0; p < 2; ++p) {
            int idx = p * 256 + t;            // 512 uint4 = 64 x 64 bf16
            int row = idx >> 3, c4 = idx & 7;
            int gm = m0 + row;
            uint4 v = make_uint4(0, 0, 0, 0);
            if (gm < M) v = *(const uint4*)&Asrc[(size_t)gm * lda + kcol + c4 * 8];
            *(uint4*)&As[row][c4 * 8] = v;
        }
#pragma unroll
        for (int p = 0; p < 4; ++p) {
            int idx = p * 256 + t;            // 1024 uint4 = 128 x 64 bf16
            int n = idx >> 3, c4 = idx & 7;
            *(uint4*)&Ws[n][c4 * 8] = *(const uint4*)&Wt[(size_t)n * K + kt + c4 * 8];
        }
        __syncthreads();
#pragma unroll
        for (int kb = 0; kb < 2; ++kb) {
            frag_ab af = *(const frag_ab*)&As[wv * 16 + lm][kb * 32 + lq * 8];
#pragma unroll
            for (int tb = 0; tb < 8; ++tb) {
                frag_ab bf = *(const frag_ab*)&Ws[tb * 16 + lm][kb * 32 + lq * 8];
                acc[tb] = __builtin_amdgcn_mfma_f32_16x16x32_bf16(af, bf, acc[tb], 0, 0, 0);
            }
        }
        __syncthreads();
    }

    if constexpr (EPI == EPI_LAYER) {
        float sq[4] = {0.f, 0.f, 0.f, 0.f};
#pragma unroll
        for (int tb = 0; tb < 8; ++tb) {
            float b = bs[tb * 16 + lm];
#pragma unroll
            for (int r = 0; r < 4; ++r) {
                acc[tb][r] += b;
                sq[r] += acc[tb][r] * acc[tb][r];
            }
        }
#pragma unroll
        for (int r = 0; r < 4; ++r) part[wv * 16 + lq * 4 + r][lm] = sq[r];
        __syncthreads();
        if (t < 64) {
            float s = 0.f;
#pragma unroll
            for (int c = 0; c < 16; ++c) s += part[t][c];
            rinv[t] = 1.0f / fmaxf(sqrtf(s), 1e-12f);
        }
        __syncthreads();
#pragma unroll
        for (int r = 0; r < 4; ++r) {
            int gr = m0 + wv * 16 + lq * 4 + r;
            if (gr >= M) continue;
            float ri = rinv[wv * 16 + lq * 4 + r];
#pragma unroll
            for (int tb = 0; tb < 8; ++tb) {
                int col = tb * 16 + lm;
                float o = bfs(residbf[(size_t)gr * 128 + col]) +
                          fmaxf(acc[tb][r], 0.f) * ri;
                Cbf[(size_t)gr * 128 + col] = f2bf(o);
            }
        }
    } else {
#pragma unroll
        for (int r = 0; r < 4; ++r) {
            int gr = m0 + wv * 16 + lq * 4 + r;
            if (gr >= M) continue;
#pragma unroll
            for (int tb = 0; tb < 8; ++tb) {
                int col = tb * 16 + lm;
                float v = acc[tb][r] + bs[col];
                Cbf[(size_t)gr * ldc + col] =
                    (EPI == EPI_PQH) ? f2h(v) : f2bf(v);
            }
        }
    }
}

// ---------------------------------------------------------------------------
// x -> bf16 cast (embed input)
// ---------------------------------------------------------------------------
__global__ void cast_k(const float* __restrict__ x, unsigned short* __restrict__ xbf,
                       int n8) {
    int i = blockIdx.x * 256 + threadIdx.x;
    if (i >= n8) return;
    float4 a = *(const float4*)&x[(size_t)i * 8];
    float4 b = *(const float4*)&x[(size_t)i * 8 + 4];
    uint4 o = make_uint4(packbf(a.x, a.y), packbf(a.z, a.w),
                         packbf(b.x, b.y), packbf(b.z, b.w));
    *(uint4*)&xbf[(size_t)i * 8] = o;
}

// ---------------------------------------------------------------------------
// CSR construction -> packed pk[pos]={src,dst,eid,0} + compact srt[pos]=src
// ---------------------------------------------------------------------------
__global__ void deg_k(const int* __restrict__ dst, int* __restrict__ deg) {
    int e = blockIdx.x * 256 + threadIdx.x;
    if (e < NE) atomicAdd(&deg[dst[e]], 1);
}

__global__ void scan1_k(const int* __restrict__ deg, int* __restrict__ rp,
                        int* __restrict__ bsum) {
    __shared__ int sh[512];
    int tid = threadIdx.x;
    int i = blockIdx.x * 512 + tid;
    int v = (i < NN) ? deg[i] : 0;
    sh[tid] = v;
    __syncthreads();
    for (int ofs = 1; ofs < 512; ofs <<= 1) {
        int x = (tid >= ofs) ? sh[tid - ofs] : 0;
        __syncthreads();
        sh[tid] += x;
        __syncthreads();
    }
    if (i < NN) rp[i] = sh[tid] - v;
    if (tid == 511) bsum[blockIdx.x] = sh[511];
}

__global__ void scan2_k(int* __restrict__ bsum, int nb) {
    __shared__ int sh[128];
    int tid = threadIdx.x;
    int v = (tid < nb) ? bsum[tid] : 0;
    sh[tid] = v;
    __syncthreads();
    for (int ofs = 1; ofs < 128; ofs <<= 1) {
        int x = (tid >= ofs) ? sh[tid - ofs] : 0;
        __syncthreads();
        sh[tid] += x;
        __syncthreads();
    }
    if (tid < nb) bsum[tid] = sh[tid] - v;
}

__global__ void scan3_k(int* __restrict__ rp, const int* __restrict__ bsum,
                        const int* __restrict__ deg, float* __restrict__ invd) {
    int i = blockIdx.x * 512 + threadIdx.x;
    if (i < NN) {
        rp[i] += bsum[blockIdx.x];
        int d = deg[i];
        invd[i] = 1.0f / (float)(d > 1 ? d : 1);
    }
    if (i == NN) rp[NN] = NE;
}

__global__ void fill_k(const int* __restrict__ src, const int* __restrict__ dst,
                       const int* __restrict__ rp, int* __restrict__ cnt,
                       int4* __restrict__ pk, int* __restrict__ srt) {
    int e = blockIdx.x * 256 + threadIdx.x;
    if (e < NE) {
        int s = src[e];
        int d = dst[e];
        int pos = rp[d] + atomicAdd(&cnt[d], 1);
        pk[pos]  = make_int4(s, d, e, 0);
        srt[pos] = s;
    }
}

// ---------------------------------------------------------------------------
// Mean aggregation, one WAVE per node. Lane layout: 32 lanes x 8 B per row,
// wave halves process alternating neighbor rows => 1 VMEM instr / 2 rows,
// 4-pair unroll => 8 rows in flight. Halves combined via shfl_xor(32).
// ---------------------------------------------------------------------------
__launch_bounds__(256, 8)
__global__ void agg_k(const unsigned short* __restrict__ hbf,
                      const int* __restrict__ rp, const int* __restrict__ srt,
                      const float* __restrict__ invd,
                      unsigned short* __restrict__ cbf) {
    int gw   = (blockIdx.x * 256 + threadIdx.x) >> 6;   // node = global wave id
    if (gw >= NN) return;
    const int lane = threadIdx.x & 63;
    const int half = lane >> 5;          // which neighbor of the pair
    const int hl   = lane & 31;          // feature group: 4 feats (8 B)
    const int b = rp[gw], e = rp[gw + 1];
    float a0 = 0.f, a1 = 0.f, a2 = 0.f, a3 = 0.f;

    int p = b;
    for (; p + 8 <= e; p += 8) {         // 4 pairs, 8 rows in flight
        int s0 = srt[p     + half];
        int s1 = srt[p + 2 + half];
        int s2 = srt[p + 4 + half];
        int s3 = srt[p + 6 + half];
        uint2 u0 = *(const uint2*)&hbf[(size_t)s0 * 128 + hl * 4];
        uint2 u1 = *(const uint2*)&hbf[(size_t)s1 * 128 + hl * 4];
        uint2 u2 = *(const uint2*)&hbf[(size_t)s2 * 128 + hl * 4];
        uint2 u3 = *(const uint2*)&hbf[(size_t)s3 * 128 + hl * 4];
        a0 += bflo(u0.x) + bflo(u1.x) + bflo(u2.x) + bflo(u3.x);
        a1 += bfhi(u0.x) + bfhi(u1.x) + bfhi(u2.x) + bfhi(u3.x);
        a2 += bflo(u0.y) + bflo(u1.y) + bflo(u2.y) + bflo(u3.y);
        a3 += bfhi(u0.y) + bfhi(u1.y) + bfhi(u2.y) + bfhi(u3.y);
    }
    for (; p + 2 <= e; p += 2) {         // single pair
        int s = srt[p + half];
        uint2 u = *(const uint2*)&hbf[(size_t)s * 128 + hl * 4];
        a0 += bflo(u.x); a1 += bfhi(u.x);
        a2 += bflo(u.y); a3 += bfhi(u.y);
    }
    if (p < e && half == 0) {            // odd-degree tail (half 0 only)
        int s = srt[p];
        uint2 u = *(const uint2*)&hbf[(size_t)s * 128 + hl * 4];
        a0 += bflo(u.x); a1 += bfhi(u.x);
        a2 += bflo(u.y); a3 += bfhi(u.y);
    }
    // combine halves
    a0 += __shfl_xor(a0, 32, 64);
    a1 += __shfl_xor(a1, 32, 64);
    a2 += __shfl_xor(a2, 32, 64);
    a3 += __shfl_xor(a3, 32, 64);

    float iv = invd[gw];
    if (half == 0) {
        uint2 r = make_uint2(packbf(a0 * iv, a1 * iv), packbf(a2 * iv, a3 * iv));
        *(uint2*)&cbf[(size_t)gw * 128 + hl * 4] = r;
    }
}

// ---------------------------------------------------------------------------
// Prep: Wct[4][128n][256k] bf16; Wefft[256n][128k] bf16; W1tg[64n][128k] FP16;
// beff; Wembt bf16.
// ---------------------------------------------------------------------------
__global__ void prep_k(const float* __restrict__ Wconv, const float* __restrict__ W0,
                       const float* __restrict__ b0, const float* __restrict__ W1,
                       const float* __restrict__ Wemb,
                       unsigned short* __restrict__ Wct,
                       unsigned short* __restrict__ Wefft,
                       float* __restrict__ beff, unsigned short* __restrict__ W1tg,
                       unsigned short* __restrict__ Wembt) {
    int i = blockIdx.x * 256 + threadIdx.x;
    if (i < 131072) {
        int lyr = i >> 15, r = i & 32767, n = r >> 8, k = r & 255;
        Wct[i] = f2bf(Wconv[(size_t)lyr * 32768 + k * 128 + n]);
    } else if (i < 163840) {
        int j = i - 131072, n = j >> 7, k = j & 127;
        float v = (n < 128) ? W0[k * 128 + n] : W0[(128 + k) * 128 + (n - 128)];
        Wefft[j] = f2bf(v);
    } else if (i < 172032) {
        int j = i - 163840, n = j >> 7, k = j & 127;
        W1tg[j] = f2h(W1[k * 64 + n]);                 // fp16 for edge MFMA
    } else if (i < 172288) {
        int j = i - 172032;
        beff[j] = (j < 128) ? b0[j] : 0.f;
    } else if (i < 180480) {
        int j = i - 172288, n = j >> 6, k = j & 63;
        Wembt[j] = f2bf(Wemb[k * 128 + n]);
    }
}

// ---------------------------------------------------------------------------
// Fused edge readout (fp16 MFMA), CSR order, 128 edges/block, 512 threads.
// Phase 1 COALESCED: 16 consecutive lanes read one 256B pq row contiguously
// (lane c -> bytes [c*16, c*16+16)), so 4 lanes share each 64B cache line
// -> 4 TA requests/row instead of 16 (round-2 pattern was 64B-stride/lane,
// every lane on a distinct line). pk loaded broadcast (16 lanes same addr).
// Bijective XCD swizzle (m204): CSR/dst-sorted edges -> consecutive logical
// blocks share q[dst] rows; chunk them per-XCD for L2 locality.
// ---------------------------------------------------------------------------
__launch_bounds__(512, 6)
__global__ void edge_mlp_k(const unsigned short* __restrict__ pq,   // fp16 [NN][256]
                           const int4* __restrict__ pk,
                           const unsigned short* __restrict__ W1tg, // fp16 [64][128]
                           const float* __restrict__ b1,
                           const float* __restrict__ W2, const float* __restrict__ b2,
                           float* __restrict__ out)
{
    __shared__ __align__(16) unsigned short E0s[128][136];  // fp16, 34816 B
    __shared__ __align__(16) unsigned short W1s[64][136];   // fp16, 17408 B
    __shared__ int ee[128];
    const int t = threadIdx.x;

    // bijective XCD remap (nwg = 6250, 8 XCDs): hardware blocks with the
    // same (orig % 8) land on one XCD; give each XCD a contiguous logical
    // chunk so neighboring edge blocks (shared dst rows) share that XCD's L2.
    const int nwg  = gridDim.x;
    const int orig = blockIdx.x;
    const int q8   = nwg >> 3, r8 = nwg & 7;
    const int xcd  = orig & 7, slot = orig >> 3;
    const int wg   = (xcd < r8 ? xcd * (q8 + 1) : r8 * (q8 + 1) + (xcd - r8) * q8) + slot;
    const int p0 = wg * 128;

    // stage W1: 64 rows x 128 fp16 = 1024 uint4 (2 per thread)
#pragma unroll
    for (int p = 0; p < 2; ++p) {
        int i4 = p * 512 + t;                 // 0..1023
        int row = i4 >> 4;                    // /16 uint4 per row -> 0..63
        int c4  = i4 & 15;                    // uint4 within row
        *(uint4*)&W1s[row][c4 * 8] = ((const uint4*)W1tg)[i4];
    }

    // phase 1: e0 = relu(p[src] + q[dst]) packed fp16 -> E0s
    // 16 threads/row, lane c loads bytes [c*16, c*16+16) of the 256B row.
    {
        const int c = t & 15;                 // 16B chunk within row
#pragma unroll
        for (int i = 0; i < 4; ++i) {
            int r = i * 32 + (t >> 4);        // edge row 0..127
            int4 pkv = pk[p0 + r];            // broadcast within 16 lanes
            if (c == 0) ee[r] = pkv.z;
            uint4 a = *(const uint4*)(pq + (size_t)pkv.x * 256 + c * 8);
            uint4 b = *(const uint4*)(pq + (size_t)pkv.y * 256 + 128 + c * 8);
            uint4 rr = make_uint4(pk_add_relu(a.x, b.x), pk_add_relu(a.y, b.y),
                                  pk_add_relu(a.z, b.z), pk_add_relu(a.w, b.w));
            *(uint4*)&E0s[r][c * 8] = rr;
        }
    }
    __syncthreads();                 // single barrier

    // phase 2: fp16 MFMA. wave wv: edges [16wv,16wv+16) x 64 outs.
    const int wv = t >> 6, l = t & 63, lq = l >> 4, lm = l & 15;
    frag_cd acc[4];
#pragma unroll
    for (int tb = 0; tb < 4; ++tb) acc[tb] = (frag_cd){0.f, 0.f, 0.f, 0.f};
    const int erow = wv * 16 + lm;
#pragma unroll
    for (int kb = 0; kb < 4; ++kb) {
        frag_h af = *(const frag_h*)&E0s[erow][kb * 32 + lq * 8];
#pragma unroll
        for (int tb = 0; tb < 4; ++tb) {
            frag_h bf = *(const frag_h*)&W1s[tb * 16 + lm][kb * 32 + lq * 8];
            acc[tb] = __builtin_amdgcn_mfma_f32_16x16x32_f16(af, bf, acc[tb], 0, 0, 0);
        }
    }

    // phase 3: in-register MLP2 (b1/W2 direct from global, L2-resident)
    float b1v[4], w20[4], w21[4];
#pragma unroll
    for (int tb = 0; tb < 4; ++tb) {
        int o = tb * 16 + lm;
        b1v[tb] = b1[o];
        w20[tb] = W2[o * 2];
        w21[tb] = W2[o * 2 + 1];
    }
    const float bo0 = b2[0], bo1 = b2[1];
#pragma unroll
    for (int r = 0; r < 4; ++r) {
        float s0 = 0.f, s1 = 0.f;
#pragma unroll
        for (int tb = 0; tb < 4; ++tb) {
            float e1 = fmaxf(acc[tb][r] + b1v[tb], 0.f);
            s0 += e1 * w20[tb];
            s1 += e1 * w21[tb];
        }
#pragma unroll
        for (int m = 1; m < 16; m <<= 1) {   // reduce over lm
            s0 += __shfl_xor(s0, m, 16);
            s1 += __shfl_xor(s1, m, 16);
        }
        if (lm == 0) {
            int e = wv * 16 + lq * 4 + r;    // 0..127
            *(float2*)&out[(size_t)ee[e] * 2] = make_float2(s0 + bo0, s1 + bo1);
        }
    }
}

// ---------------------------------------------------------------------------
extern "C" void kernel_launch(void* const* d_in, const int* in_sizes, int n_in,
                              void* d_out, int out_size, void* d_ws, size_t ws_size,
                              hipStream_t stream)
{
    const float* x    = (const float*)d_in[0];
    const int*   esrc = (const int*)  d_in[1];
    const int*   edst = (const int*)  d_in[2];
    const float* Wemb  = (const float*)d_in[5];
    const float* bemb  = (const float*)d_in[6];
    const float* Wconv = (const float*)d_in[7];
    const float* bconv = (const float*)d_in[8];
    const float* Wm0   = (const float*)d_in[9];
    const float* bm0   = (const float*)d_in[10];
    const float* Wm1   = (const float*)d_in[11];
    const float* bm1   = (const float*)d_in[12];
    const float* Wm2   = (const float*)d_in[13];
    const float* bm2   = (const float*)d_in[14];
    float* out = (float*)d_out;

    char* ws = (char*)d_ws;
    size_t off = 0;
    auto alloc = [&](size_t bytes) -> void* {
        void* p = ws + off;
        off = (off + bytes + 255) & ~(size_t)255;
        return p;
    };
    unsigned short* h0bf = (unsigned short*)alloc((size_t)NN * 128 * 2);
    unsigned short* h1bf = (unsigned short*)alloc((size_t)NN * 128 * 2);
    unsigned short* cbf  = (unsigned short*)alloc((size_t)NN * 128 * 2);
    unsigned short* pqb  = (unsigned short*)alloc((size_t)NN * 256 * 2);
    unsigned short* xbf  = (unsigned short*)alloc((size_t)NN * 64 * 2);
    unsigned short* Wct   = (unsigned short*)alloc(4 * 128 * 256 * 2);
    unsigned short* Wefft = (unsigned short*)alloc(256 * 128 * 2);
    float*          beff  = (float*)alloc(256 * 4);
    unsigned short* W1tg  = (unsigned short*)alloc(64 * 128 * 2);
    unsigned short* Wembt = (unsigned short*)alloc(128 * 64 * 2);
    int*   deg  = (int*)alloc((size_t)NN * 4);
    int*   rp   = (int*)alloc((size_t)(NN + 1) * 4);
    int*   cnt  = (int*)alloc((size_t)NN * 4);
    float* invd = (float*)alloc((size_t)NN * 4);
    int*   bsum = (int*)alloc(512);
    int4*  pk   = (int4*)alloc((size_t)NE * 16);
    int*   srt  = (int*)alloc((size_t)NE * 4);
    (void)ws_size; (void)in_sizes; (void)n_in; (void)out_size;

    hipMemsetAsync(deg, 0, (size_t)NN * 4, stream);
    hipMemsetAsync(cnt, 0, (size_t)NN * 4, stream);

    // cast x -> bf16; weight prep
    cast_k<<<(NN * 64 / 8 + 255) / 256, 256, 0, stream>>>(x, xbf, NN * 64 / 8);
    prep_k<<<(180480 + 255) / 256, 256, 0, stream>>>(
        Wconv, Wm0, bm0, Wm1, Wemb, Wct, Wefft, beff, W1tg, Wembt);

    // CSR build (packed + compact srt)
    deg_k  <<<(NE + 255) / 256, 256, 0, stream>>>(edst, deg);
    scan1_k<<<(NN + 511) / 512, 512, 0, stream>>>(deg, rp, bsum);
    scan2_k<<<1, 128, 0, stream>>>(bsum, (NN + 511) / 512);
    scan3_k<<<(NN + 511) / 512, 512, 0, stream>>>(rp, bsum, deg, invd);
    fill_k <<<(NE + 255) / 256, 256, 0, stream>>>(esrc, edst, rp, cnt, pk, srt);

    // h0 = bf16(x @ Wemb + bemb) via MFMA
    mfma_gemm_k<EPI_PQBF><<<dim3((NN + 63) / 64, 1), 256, 0, stream>>>(
        xbf, nullptr, 64, 1 << 30, Wembt, bemb, h0bf, 128, nullptr, NN, 64);

    // 4 SAGE layers (MFMA, bf16 residual)
    unsigned short* hcbf = h0bf; unsigned short* hnbf = h1bf;
    for (int l = 0; l < 4; ++l) {
        agg_k<<<(NN + 3) / 4, 256, 0, stream>>>(hcbf, rp, srt, invd, cbf);
        mfma_gemm_k<EPI_LAYER><<<dim3((NN + 63) / 64, 1), 256, 0, stream>>>(
            hcbf, cbf, 128, 128, Wct + (size_t)l * 128 * 256,
            bconv + (size_t)l * 128, hnbf, 128, hcbf, NN, 256);
        unsigned short* tb = hcbf; hcbf = hnbf; hnbf = tb;
    }
    // after 4 layers: hcbf == h0bf

    // pq = fp16(h @ Weff + beff)  [NN][256]  (fp16 feeds edge pipeline)
    mfma_gemm_k<EPI_PQH><<<dim3((NN + 63) / 64, 2), 256, 0, stream>>>(
        hcbf, nullptr, 128, 1 << 30, Wefft, beff, pqb, 256, nullptr, NN, 128);

    // fused edge readout (coalesced gathers, XCD-swizzled, 128 edges/block)
    edge_mlp_k<<<NE / 128, 512, 0, stream>>>(pqb, pk, W1tg, bm1, Wm2, bm2, out);
}

// Round 5
// 444.071 us; speedup vs baseline: 1.2126x; 1.0690x over previous
//
#include <hip/hip_runtime.h>

constexpr int NN  = 50000;   // nodes
constexpr int NE  = 800000;  // edges

using frag_ab = __attribute__((ext_vector_type(8))) short;     // 8 bf16
using frag_h  = __attribute__((ext_vector_type(8))) _Float16;  // 8 fp16
using frag_cd = __attribute__((ext_vector_type(4))) float;     // 4 fp32
using h2      = __attribute__((ext_vector_type(2))) _Float16;  // 2 fp16

__device__ __forceinline__ unsigned short f2bf(float f) {   // RNE
    union { float f; unsigned u; } v; v.f = f;
    unsigned r = v.u + 0x7FFFu + ((v.u >> 16) & 1u);
    return (unsigned short)(r >> 16);
}
__device__ __forceinline__ unsigned short f2h(float f) {    // RNE via HW cvt
    union { _Float16 h; unsigned short u; } v; v.h = (_Float16)f; return v.u;
}
__device__ __forceinline__ float bflo(unsigned u) {
    union { unsigned u; float f; } v; v.u = u << 16; return v.f;
}
__device__ __forceinline__ float bfhi(unsigned u) {
    union { unsigned u; float f; } v; v.u = u & 0xFFFF0000u; return v.f;
}
__device__ __forceinline__ float bfs(unsigned short u) {
    union { unsigned u; float f; } v; v.u = (unsigned)u << 16; return v.f;
}
__device__ __forceinline__ unsigned packbf(float a, float b) {       // RNE
    return (unsigned)f2bf(a) | ((unsigned)f2bf(b) << 16);
}
// packed fp16 relu(a+b): clang lowers to v_pk_add_f16 + v_pk_max_f16 (2 VALU ops)
__device__ __forceinline__ unsigned pk_add_relu(unsigned a, unsigned b) {
    union Cu { unsigned u; h2 h; };
    Cu ua; ua.u = a;
    Cu ub; ub.u = b;
    h2 s = ua.h + ub.h;
    h2 z; z[0] = (_Float16)0.f; z[1] = (_Float16)0.f;
    Cu r; r.h = __builtin_elementwise_max(s, z);
    return r.u;
}

enum { EPI_LAYER = 1, EPI_PQBF = 2, EPI_PQH = 3 };

// ---------------------------------------------------------------------------
// MFMA bf16 GEMM. Block: 64 rows x 128 cols, 4 waves, BK=64.
// EPI_PQH writes fp16 output (feeds the fp16 edge pipeline).
// ---------------------------------------------------------------------------
template<int EPI>
__launch_bounds__(256, 4)
__global__ void mfma_gemm_k(const unsigned short* __restrict__ A0,
                            const unsigned short* __restrict__ A1,
                            int lda, int kSplit,
                            const unsigned short* __restrict__ Wt,
                            const float* __restrict__ bias,
                            unsigned short* __restrict__ Cbf, int ldc,
                            const unsigned short* __restrict__ residbf,
                            int M, int K)
{
    __shared__ __align__(16) unsigned short As[64][72];    // [row][k], pad 8
    __shared__ __align__(16) unsigned short Ws[128][72];   // [n][k],  pad 8
    __shared__ float bs[128];
    __shared__ float part[(EPI == EPI_LAYER) ? 64 : 1][17];
    __shared__ float rinv[(EPI == EPI_LAYER) ? 64 : 1];

    const int t  = threadIdx.x;
    const int by = blockIdx.y;
    Wt   += (size_t)by * 128 * K;
    bias += (size_t)by * 128;
    if constexpr (EPI != EPI_LAYER) Cbf += (size_t)by * 128;
    const int m0 = blockIdx.x * 64;

    if (t < 128) bs[t] = bias[t];

    const int wv = t >> 6, l = t & 63, lq = l >> 4, lm = l & 15;
    frag_cd acc[8];
#pragma unroll
    for (int tb = 0; tb < 8; ++tb) acc[tb] = (frag_cd){0.f, 0.f, 0.f, 0.f};

    for (int kt = 0; kt < K; kt += 64) {
        const unsigned short* Asrc = (kt < kSplit) ? A0 : A1;
        const int kcol = (kt < kSplit) ? kt : kt - kSplit;
#pragma unroll
        for (int p = 0; p < 2; ++p) {
            int idx = p * 256 + t;            // 512 uint4 = 64 x 64 bf16
            int row = idx >> 3, c4 = idx & 7;
            int gm = m0 + row;
            uint4 v = make_uint4(0, 0, 0, 0);
            if (gm < M) v = *(const uint4*)&Asrc[(size_t)gm * lda + kcol + c4 * 8];
            *(uint4*)&As[row][c4 * 8] = v;
        }
#pragma unroll
        for (int p = 0; p < 4; ++p) {
            int idx = p * 256 + t;            // 1024 uint4 = 128 x 64 bf16
            int n = idx >> 3, c4 = idx & 7;
            *(uint4*)&Ws[n][c4 * 8] = *(const uint4*)&Wt[(size_t)n * K + kt + c4 * 8];
        }
        __syncthreads();
#pragma unroll
        for (int kb = 0; kb < 2; ++kb) {
            frag_ab af = *(const frag_ab*)&As[wv * 16 + lm][kb * 32 + lq * 8];
#pragma unroll
            for (int tb = 0; tb < 8; ++tb) {
                frag_ab bf = *(const frag_ab*)&Ws[tb * 16 + lm][kb * 32 + lq * 8];
                acc[tb] = __builtin_amdgcn_mfma_f32_16x16x32_bf16(af, bf, acc[tb], 0, 0, 0);
            }
        }
        __syncthreads();
    }

    if constexpr (EPI == EPI_LAYER) {
        float sq[4] = {0.f, 0.f, 0.f, 0.f};
#pragma unroll
        for (int tb = 0; tb < 8; ++tb) {
            float b = bs[tb * 16 + lm];
#pragma unroll
            for (int r = 0; r < 4; ++r) {
                acc[tb][r] += b;
                sq[r] += acc[tb][r] * acc[tb][r];
            }
        }
#pragma unroll
        for (int r = 0; r < 4; ++r) part[wv * 16 + lq * 4 + r][lm] = sq[r];
        __syncthreads();
        if (t < 64) {
            float s = 0.f;
#pragma unroll
            for (int c = 0; c < 16; ++c) s += part[t][c];
            rinv[t] = 1.0f / fmaxf(sqrtf(s), 1e-12f);
        }
        __syncthreads();
#pragma unroll
        for (int r = 0; r < 4; ++r) {
            int gr = m0 + wv * 16 + lq * 4 + r;
            if (gr >= M) continue;
            float ri = rinv[wv * 16 + lq * 4 + r];
#pragma unroll
            for (int tb = 0; tb < 8; ++tb) {
                int col = tb * 16 + lm;
                float o = bfs(residbf[(size_t)gr * 128 + col]) +
                          fmaxf(acc[tb][r], 0.f) * ri;
                Cbf[(size_t)gr * 128 + col] = f2bf(o);
            }
        }
    } else {
#pragma unroll
        for (int r = 0; r < 4; ++r) {
            int gr = m0 + wv * 16 + lq * 4 + r;
            if (gr >= M) continue;
#pragma unroll
            for (int tb = 0; tb < 8; ++tb) {
                int col = tb * 16 + lm;
                float v = acc[tb][r] + bs[col];
                Cbf[(size_t)gr * ldc + col] =
                    (EPI == EPI_PQH) ? f2h(v) : f2bf(v);
            }
        }
    }
}

// ---------------------------------------------------------------------------
// x -> bf16 cast (embed input)
// ---------------------------------------------------------------------------
__global__ void cast_k(const float* __restrict__ x, unsigned short* __restrict__ xbf,
                       int n8) {
    int i = blockIdx.x * 256 + threadIdx.x;
    if (i >= n8) return;
    float4 a = *(const float4*)&x[(size_t)i * 8];
    float4 b = *(const float4*)&x[(size_t)i * 8 + 4];
    uint4 o = make_uint4(packbf(a.x, a.y), packbf(a.z, a.w),
                         packbf(b.x, b.y), packbf(b.z, b.w));
    *(uint4*)&xbf[(size_t)i * 8] = o;
}

// ---------------------------------------------------------------------------
// CSR construction. deg_k also records each edge's slot within its dst's
// list (ofs[e] = atomicAdd return, coalesced write) so fill_k needs NO
// atomics and no cnt[] array.
// ---------------------------------------------------------------------------
__global__ void deg_k(const int* __restrict__ dst, int* __restrict__ deg,
                      int* __restrict__ ofs) {
    int e = blockIdx.x * 256 + threadIdx.x;
    if (e < NE) ofs[e] = atomicAdd(&deg[dst[e]], 1);
}

__global__ void scan1_k(const int* __restrict__ deg, int* __restrict__ rp,
                        int* __restrict__ bsum) {
    __shared__ int sh[512];
    int tid = threadIdx.x;
    int i = blockIdx.x * 512 + tid;
    int v = (i < NN) ? deg[i] : 0;
    sh[tid] = v;
    __syncthreads();
    for (int ofs = 1; ofs < 512; ofs <<= 1) {
        int x = (tid >= ofs) ? sh[tid - ofs] : 0;
        __syncthreads();
        sh[tid] += x;
        __syncthreads();
    }
    if (i < NN) rp[i] = sh[tid] - v;
    if (tid == 511) bsum[blockIdx.x] = sh[511];
}

__global__ void scan2_k(int* __restrict__ bsum, int nb) {
    __shared__ int sh[128];
    int tid = threadIdx.x;
    int v = (tid < nb) ? bsum[tid] : 0;
    sh[tid] = v;
    __syncthreads();
    for (int ofs = 1; ofs < 128; ofs <<= 1) {
        int x = (tid >= ofs) ? sh[tid - ofs] : 0;
        __syncthreads();
        sh[tid] += x;
        __syncthreads();
    }
    if (tid < nb) bsum[tid] = sh[tid] - v;
}

__global__ void scan3_k(int* __restrict__ rp, const int* __restrict__ bsum,
                        const int* __restrict__ deg, float* __restrict__ invd) {
    int i = blockIdx.x * 512 + threadIdx.x;
    if (i < NN) {
        rp[i] += bsum[blockIdx.x];
        int d = deg[i];
        invd[i] = 1.0f / (float)(d > 1 ? d : 1);
    }
    if (i == NN) rp[NN] = NE;
}

// atomic-free fill: pos = rp[dst] + ofs[e]; 12B scatter (srt 4B + de 8B)
__global__ void fill_k(const int* __restrict__ src, const int* __restrict__ dst,
                       const int* __restrict__ rp, const int* __restrict__ ofs,
                       int* __restrict__ srt, int2* __restrict__ de) {
    int e = blockIdx.x * 256 + threadIdx.x;
    if (e < NE) {
        int d = dst[e];
        int pos = rp[d] + ofs[e];
        srt[pos] = src[e];
        de[pos]  = make_int2(d, e);
    }
}

// ---------------------------------------------------------------------------
// Mean aggregation, one WAVE per node. Lane layout: 32 lanes x 8 B per row,
// wave halves process alternating neighbor rows => 1 VMEM instr / 2 rows,
// 4-pair unroll => 8 rows in flight. Halves combined via shfl_xor(32).
// ---------------------------------------------------------------------------
__launch_bounds__(256, 8)
__global__ void agg_k(const unsigned short* __restrict__ hbf,
                      const int* __restrict__ rp, const int* __restrict__ srt,
                      const float* __restrict__ invd,
                      unsigned short* __restrict__ cbf) {
    int gw   = (blockIdx.x * 256 + threadIdx.x) >> 6;   // node = global wave id
    if (gw >= NN) return;
    const int lane = threadIdx.x & 63;
    const int half = lane >> 5;          // which neighbor of the pair
    const int hl   = lane & 31;          // feature group: 4 feats (8 B)
    const int b = rp[gw], e = rp[gw + 1];
    float a0 = 0.f, a1 = 0.f, a2 = 0.f, a3 = 0.f;

    int p = b;
    for (; p + 8 <= e; p += 8) {         // 4 pairs, 8 rows in flight
        int s0 = srt[p     + half];
        int s1 = srt[p + 2 + half];
        int s2 = srt[p + 4 + half];
        int s3 = srt[p + 6 + half];
        uint2 u0 = *(const uint2*)&hbf[(size_t)s0 * 128 + hl * 4];
        uint2 u1 = *(const uint2*)&hbf[(size_t)s1 * 128 + hl * 4];
        uint2 u2 = *(const uint2*)&hbf[(size_t)s2 * 128 + hl * 4];
        uint2 u3 = *(const uint2*)&hbf[(size_t)s3 * 128 + hl * 4];
        a0 += bflo(u0.x) + bflo(u1.x) + bflo(u2.x) + bflo(u3.x);
        a1 += bfhi(u0.x) + bfhi(u1.x) + bfhi(u2.x) + bfhi(u3.x);
        a2 += bflo(u0.y) + bflo(u1.y) + bflo(u2.y) + bflo(u3.y);
        a3 += bfhi(u0.y) + bfhi(u1.y) + bfhi(u2.y) + bfhi(u3.y);
    }
    for (; p + 2 <= e; p += 2) {         // single pair
        int s = srt[p + half];
        uint2 u = *(const uint2*)&hbf[(size_t)s * 128 + hl * 4];
        a0 += bflo(u.x); a1 += bfhi(u.x);
        a2 += bflo(u.y); a3 += bfhi(u.y);
    }
    if (p < e && half == 0) {            // odd-degree tail (half 0 only)
        int s = srt[p];
        uint2 u = *(const uint2*)&hbf[(size_t)s * 128 + hl * 4];
        a0 += bflo(u.x); a1 += bfhi(u.x);
        a2 += bflo(u.y); a3 += bfhi(u.y);
    }
    // combine halves
    a0 += __shfl_xor(a0, 32, 64);
    a1 += __shfl_xor(a1, 32, 64);
    a2 += __shfl_xor(a2, 32, 64);
    a3 += __shfl_xor(a3, 32, 64);

    float iv = invd[gw];
    if (half == 0) {
        uint2 r = make_uint2(packbf(a0 * iv, a1 * iv), packbf(a2 * iv, a3 * iv));
        *(uint2*)&cbf[(size_t)gw * 128 + hl * 4] = r;
    }
}

// ---------------------------------------------------------------------------
// Prep: Wct[4][128n][256k] bf16; Wefft[256n][128k] bf16; W1tg[64n][128k] FP16;
// beff; Wembt bf16.
// ---------------------------------------------------------------------------
__global__ void prep_k(const float* __restrict__ Wconv, const float* __restrict__ W0,
                       const float* __restrict__ b0, const float* __restrict__ W1,
                       const float* __restrict__ Wemb,
                       unsigned short* __restrict__ Wct,
                       unsigned short* __restrict__ Wefft,
                       float* __restrict__ beff, unsigned short* __restrict__ W1tg,
                       unsigned short* __restrict__ Wembt) {
    int i = blockIdx.x * 256 + threadIdx.x;
    if (i < 131072) {
        int lyr = i >> 15, r = i & 32767, n = r >> 8, k = r & 255;
        Wct[i] = f2bf(Wconv[(size_t)lyr * 32768 + k * 128 + n]);
    } else if (i < 163840) {
        int j = i - 131072, n = j >> 7, k = j & 127;
        float v = (n < 128) ? W0[k * 128 + n] : W0[(128 + k) * 128 + (n - 128)];
        Wefft[j] = f2bf(v);
    } else if (i < 172032) {
        int j = i - 163840, n = j >> 7, k = j & 127;
        W1tg[j] = f2h(W1[k * 64 + n]);                 // fp16 for edge MFMA
    } else if (i < 172288) {
        int j = i - 172032;
        beff[j] = (j < 128) ? b0[j] : 0.f;
    } else if (i < 180480) {
        int j = i - 172288, n = j >> 6, k = j & 63;
        Wembt[j] = f2bf(Wemb[k * 128 + n]);
    }
}

// ---------------------------------------------------------------------------
// Fused edge readout (fp16 MFMA), CSR order, 128 edges/block, 512 threads,
// single barrier, in-register MLP2 (shfl reduce). Round-2 structure (best
// measured 62.3us); edge meta from srt (src) + de ({dst,eid}).
// ---------------------------------------------------------------------------
__launch_bounds__(512, 6)
__global__ void edge_mlp_k(const unsigned short* __restrict__ pq,   // fp16 [NN][256]
                           const int* __restrict__ srt,
                           const int2* __restrict__ de,
                           const unsigned short* __restrict__ W1tg, // fp16 [64][128]
                           const float* __restrict__ b1,
                           const float* __restrict__ W2, const float* __restrict__ b2,
                           float* __restrict__ out)
{
    __shared__ __align__(16) unsigned short E0s[128][136];  // fp16, 34816 B
    __shared__ __align__(16) unsigned short W1s[64][136];   // fp16, 17408 B
    __shared__ int ee[128];
    const int t = threadIdx.x;
    const int p0 = blockIdx.x * 128;

    // stage W1: 64 rows x 128 fp16 = 1024 uint4 (2 per thread)
#pragma unroll
    for (int p = 0; p < 2; ++p) {
        int i4 = p * 512 + t;                 // 0..1023
        int row = i4 >> 4;                    // /16 uint4 per row -> 0..63
        int c4  = i4 & 15;                    // uint4 within row
        *(uint4*)&W1s[row][c4 * 8] = ((const uint4*)W1tg)[i4];
    }

    // phase 1: e0 = relu(p[src] + q[dst]) packed fp16 -> E0s (4 threads/edge)
    {
        const int ei = t >> 2;                // 0..127
        const int fs = (t & 3) * 32;
        int  sv  = srt[p0 + ei];
        int2 dev = de[p0 + ei];
        if ((t & 3) == 0) ee[ei] = dev.y;
        const unsigned short* pr = pq + (size_t)sv * 256 + fs;
        const unsigned short* qr = pq + (size_t)dev.x * 256 + 128 + fs;
#pragma unroll
        for (int j = 0; j < 4; ++j) {
            uint4 a = *(const uint4*)(pr + j * 8);
            uint4 b = *(const uint4*)(qr + j * 8);
            uint4 r = make_uint4(pk_add_relu(a.x, b.x), pk_add_relu(a.y, b.y),
                                 pk_add_relu(a.z, b.z), pk_add_relu(a.w, b.w));
            *(uint4*)&E0s[ei][fs + j * 8] = r;
        }
    }
    __syncthreads();                 // single barrier

    // phase 2: fp16 MFMA. wave wv: edges [16wv,16wv+16) x 64 outs.
    const int wv = t >> 6, l = t & 63, lq = l >> 4, lm = l & 15;
    frag_cd acc[4];
#pragma unroll
    for (int tb = 0; tb < 4; ++tb) acc[tb] = (frag_cd){0.f, 0.f, 0.f, 0.f};
    const int erow = wv * 16 + lm;
#pragma unroll
    for (int kb = 0; kb < 4; ++kb) {
        frag_h af = *(const frag_h*)&E0s[erow][kb * 32 + lq * 8];
#pragma unroll
        for (int tb = 0; tb < 4; ++tb) {
            frag_h bf = *(const frag_h*)&W1s[tb * 16 + lm][kb * 32 + lq * 8];
            acc[tb] = __builtin_amdgcn_mfma_f32_16x16x32_f16(af, bf, acc[tb], 0, 0, 0);
        }
    }

    // phase 3: in-register MLP2 (b1/W2 direct from global, L2-resident)
    float b1v[4], w20[4], w21[4];
#pragma unroll
    for (int tb = 0; tb < 4; ++tb) {
        int o = tb * 16 + lm;
        b1v[tb] = b1[o];
        w20[tb] = W2[o * 2];
        w21[tb] = W2[o * 2 + 1];
    }
    const float bo0 = b2[0], bo1 = b2[1];
#pragma unroll
    for (int r = 0; r < 4; ++r) {
        float s0 = 0.f, s1 = 0.f;
#pragma unroll
        for (int tb = 0; tb < 4; ++tb) {
            float e1 = fmaxf(acc[tb][r] + b1v[tb], 0.f);
            s0 += e1 * w20[tb];
            s1 += e1 * w21[tb];
        }
#pragma unroll
        for (int m = 1; m < 16; m <<= 1) {   // reduce over lm
            s0 += __shfl_xor(s0, m, 16);
            s1 += __shfl_xor(s1, m, 16);
        }
        if (lm == 0) {
            int e = wv * 16 + lq * 4 + r;    // 0..127
            *(float2*)&out[(size_t)ee[e] * 2] = make_float2(s0 + bo0, s1 + bo1);
        }
    }
}

// ---------------------------------------------------------------------------
extern "C" void kernel_launch(void* const* d_in, const int* in_sizes, int n_in,
                              void* d_out, int out_size, void* d_ws, size_t ws_size,
                              hipStream_t stream)
{
    const float* x    = (const float*)d_in[0];
    const int*   esrc = (const int*)  d_in[1];
    const int*   edst = (const int*)  d_in[2];
    const float* Wemb  = (const float*)d_in[5];
    const float* bemb  = (const float*)d_in[6];
    const float* Wconv = (const float*)d_in[7];
    const float* bconv = (const float*)d_in[8];
    const float* Wm0   = (const float*)d_in[9];
    const float* bm0   = (const float*)d_in[10];
    const float* Wm1   = (const float*)d_in[11];
    const float* bm1   = (const float*)d_in[12];
    const float* Wm2   = (const float*)d_in[13];
    const float* bm2   = (const float*)d_in[14];
    float* out = (float*)d_out;

    char* ws = (char*)d_ws;
    size_t off = 0;
    auto alloc = [&](size_t bytes) -> void* {
        void* p = ws + off;
        off = (off + bytes + 255) & ~(size_t)255;
        return p;
    };
    unsigned short* h0bf = (unsigned short*)alloc((size_t)NN * 128 * 2);
    unsigned short* h1bf = (unsigned short*)alloc((size_t)NN * 128 * 2);
    unsigned short* cbf  = (unsigned short*)alloc((size_t)NN * 128 * 2);
    unsigned short* pqb  = (unsigned short*)alloc((size_t)NN * 256 * 2);
    unsigned short* xbf  = (unsigned short*)alloc((size_t)NN * 64 * 2);
    unsigned short* Wct   = (unsigned short*)alloc(4 * 128 * 256 * 2);
    unsigned short* Wefft = (unsigned short*)alloc(256 * 128 * 2);
    float*          beff  = (float*)alloc(256 * 4);
    unsigned short* W1tg  = (unsigned short*)alloc(64 * 128 * 2);
    unsigned short* Wembt = (unsigned short*)alloc(128 * 64 * 2);
    int*   deg  = (int*)alloc((size_t)NN * 4);
    int*   rp   = (int*)alloc((size_t)(NN + 1) * 4);
    float* invd = (float*)alloc((size_t)NN * 4);
    int*   bsum = (int*)alloc(512);
    int*   ofs  = (int*)alloc((size_t)NE * 4);
    int*   srt  = (int*)alloc((size_t)NE * 4);
    int2*  de   = (int2*)alloc((size_t)NE * 8);
    (void)ws_size; (void)in_sizes; (void)n_in; (void)out_size;

    hipMemsetAsync(deg, 0, (size_t)NN * 4, stream);

    // cast x -> bf16; weight prep
    cast_k<<<(NN * 64 / 8 + 255) / 256, 256, 0, stream>>>(x, xbf, NN * 64 / 8);
    prep_k<<<(180480 + 255) / 256, 256, 0, stream>>>(
        Wconv, Wm0, bm0, Wm1, Wemb, Wct, Wefft, beff, W1tg, Wembt);

    // CSR build: deg (+per-edge slot), scan, atomic-free fill
    deg_k  <<<(NE + 255) / 256, 256, 0, stream>>>(edst, deg, ofs);
    scan1_k<<<(NN + 511) / 512, 512, 0, stream>>>(deg, rp, bsum);
    scan2_k<<<1, 128, 0, stream>>>(bsum, (NN + 511) / 512);
    scan3_k<<<(NN + 511) / 512, 512, 0, stream>>>(rp, bsum, deg, invd);
    fill_k <<<(NE + 255) / 256, 256, 0, stream>>>(esrc, edst, rp, ofs, srt, de);

    // h0 = bf16(x @ Wemb + bemb) via MFMA
    mfma_gemm_k<EPI_PQBF><<<dim3((NN + 63) / 64, 1), 256, 0, stream>>>(
        xbf, nullptr, 64, 1 << 30, Wembt, bemb, h0bf, 128, nullptr, NN, 64);

    // 4 SAGE layers (MFMA, bf16 residual)
    unsigned short* hcbf = h0bf; unsigned short* hnbf = h1bf;
    for (int l = 0; l < 4; ++l) {
        agg_k<<<(NN + 3) / 4, 256, 0, stream>>>(hcbf, rp, srt, invd, cbf);
        mfma_gemm_k<EPI_LAYER><<<dim3((NN + 63) / 64, 1), 256, 0, stream>>>(
            hcbf, cbf, 128, 128, Wct + (size_t)l * 128 * 256,
            bconv + (size_t)l * 128, hnbf, 128, hcbf, NN, 256);
        unsigned short* tb = hcbf; hcbf = hnbf; hnbf = tb;
    }
    // after 4 layers: hcbf == h0bf

    // pq = fp16(h @ Weff + beff)  [NN][256]  (fp16 feeds edge pipeline)
    mfma_gemm_k<EPI_PQH><<<dim3((NN + 63) / 64, 2), 256, 0, stream>>>(
        hcbf, nullptr, 128, 1 << 30, Wefft, beff, pqb, 256, nullptr, NN, 128);

    // fused edge readout (CSR order, 128 edges/block, single barrier)
    edge_mlp_k<<<NE / 128, 512, 0, stream>>>(pqb, srt, de, W1tg, bm1, Wm2, bm2, out);
}

// Round 6
// 430.667 us; speedup vs baseline: 1.2503x; 1.0311x over previous
//
#include <hip/hip_runtime.h>

constexpr int NN  = 50000;   // nodes
constexpr int NE  = 800000;  // edges

using frag_ab = __attribute__((ext_vector_type(8))) short;     // 8 bf16
using frag_h  = __attribute__((ext_vector_type(8))) _Float16;  // 8 fp16
using frag_cd = __attribute__((ext_vector_type(4))) float;     // 4 fp32
using h2      = __attribute__((ext_vector_type(2))) _Float16;  // 2 fp16

__device__ __forceinline__ unsigned short f2bf(float f) {   // RNE
    union { float f; unsigned u; } v; v.f = f;
    unsigned r = v.u + 0x7FFFu + ((v.u >> 16) & 1u);
    return (unsigned short)(r >> 16);
}
__device__ __forceinline__ unsigned short f2h(float f) {    // RNE via HW cvt
    union { _Float16 h; unsigned short u; } v; v.h = (_Float16)f; return v.u;
}
__device__ __forceinline__ float bflo(unsigned u) {
    union { unsigned u; float f; } v; v.u = u << 16; return v.f;
}
__device__ __forceinline__ float bfhi(unsigned u) {
    union { unsigned u; float f; } v; v.u = u & 0xFFFF0000u; return v.f;
}
__device__ __forceinline__ float bfs(unsigned short u) {
    union { unsigned u; float f; } v; v.u = (unsigned)u << 16; return v.f;
}
__device__ __forceinline__ unsigned packbf(float a, float b) {       // RNE
    return (unsigned)f2bf(a) | ((unsigned)f2bf(b) << 16);
}
// packed fp16 relu(a+b): clang lowers to v_pk_add_f16 + v_pk_max_f16 (2 VALU ops)
__device__ __forceinline__ unsigned pk_add_relu(unsigned a, unsigned b) {
    union Cu { unsigned u; h2 h; };
    Cu ua; ua.u = a;
    Cu ub; ub.u = b;
    h2 s = ua.h + ub.h;
    h2 z; z[0] = (_Float16)0.f; z[1] = (_Float16)0.f;
    Cu r; r.h = __builtin_elementwise_max(s, z);
    return r.u;
}

// global -> LDS direct DMA, 16 B/lane. LDS dest = wave-uniform base + lane*16
// (m104); global src is per-lane. Literal size arg required.
__device__ __forceinline__ void gload_lds16(const unsigned short* g,
                                            unsigned short* l) {
    __builtin_amdgcn_global_load_lds(
        (const __attribute__((address_space(1))) unsigned int*)g,
        (__attribute__((address_space(3))) unsigned int*)l, 16, 0, 0);
}

enum { EPI_LAYER = 1, EPI_PQBF = 2, EPI_PQH = 3 };

// ---------------------------------------------------------------------------
// MFMA bf16 GEMM. Block: 64 rows x 128 cols, 4 waves, BK=64.
// Staging via global_load_lds (linear LDS, no pad). Tail rows (gm >= M) read
// garbage from adjacent workspace -- harmless: MFMA row i only affects output
// row i, and rows >= M are never stored.
// EPI_PQH writes fp16 output (feeds the fp16 edge pipeline).
// ---------------------------------------------------------------------------
template<int EPI>
__launch_bounds__(256, 4)
__global__ void mfma_gemm_k(const unsigned short* __restrict__ A0,
                            const unsigned short* __restrict__ A1,
                            int lda, int kSplit,
                            const unsigned short* __restrict__ Wt,
                            const float* __restrict__ bias,
                            unsigned short* __restrict__ Cbf, int ldc,
                            const unsigned short* __restrict__ residbf,
                            int M, int K)
{
    __shared__ __align__(16) unsigned short As[64][64];    // 8 KB, linear
    __shared__ __align__(16) unsigned short Ws[128][64];   // 16 KB, linear
    __shared__ float bs[128];
    __shared__ float part[(EPI == EPI_LAYER) ? 64 : 1][17];
    __shared__ float rinv[(EPI == EPI_LAYER) ? 64 : 1];

    const int t  = threadIdx.x;
    const int by = blockIdx.y;
    Wt   += (size_t)by * 128 * K;
    bias += (size_t)by * 128;
    if constexpr (EPI != EPI_LAYER) Cbf += (size_t)by * 128;
    const int m0 = blockIdx.x * 64;

    if (t < 128) bs[t] = bias[t];

    const int wv = t >> 6, l = t & 63, lq = l >> 4, lm = l & 15;
    const int sr = l >> 3;            // staging: row within 8-row group
    const int sc = (l & 7) * 8;       // staging: col element offset (16 B)
    frag_cd acc[8];
#pragma unroll
    for (int tb = 0; tb < 8; ++tb) acc[tb] = (frag_cd){0.f, 0.f, 0.f, 0.f};

    for (int kt = 0; kt < K; kt += 64) {
        const unsigned short* Asrc = (kt < kSplit) ? A0 : A1;
        const int kcol = (kt < kSplit) ? kt : kt - kSplit;
        // A tile 64x64: wave wv stages rows [16wv,16wv+16), 2 DMA x 8 rows
#pragma unroll
        for (int i = 0; i < 2; ++i) {
            int row = wv * 16 + i * 8;
            int gm  = m0 + row + sr;
            gload_lds16(&Asrc[(size_t)gm * lda + kcol + sc], &As[row][0]);
        }
        // W tile 128x64: wave wv stages rows [32wv,32wv+32), 4 DMA x 8 rows
#pragma unroll
        for (int i = 0; i < 4; ++i) {
            int row = wv * 32 + i * 8;
            int n   = row + sr;
            gload_lds16(&Wt[(size_t)n * K + kt + sc], &Ws[row][0]);
        }
        __syncthreads();
#pragma unroll
        for (int kb = 0; kb < 2; ++kb) {
            frag_ab af = *(const frag_ab*)&As[wv * 16 + lm][kb * 32 + lq * 8];
#pragma unroll
            for (int tb = 0; tb < 8; ++tb) {
                frag_ab bf = *(const frag_ab*)&Ws[tb * 16 + lm][kb * 32 + lq * 8];
                acc[tb] = __builtin_amdgcn_mfma_f32_16x16x32_bf16(af, bf, acc[tb], 0, 0, 0);
            }
        }
        __syncthreads();
    }

    if constexpr (EPI == EPI_LAYER) {
        float sq[4] = {0.f, 0.f, 0.f, 0.f};
#pragma unroll
        for (int tb = 0; tb < 8; ++tb) {
            float b = bs[tb * 16 + lm];
#pragma unroll
            for (int r = 0; r < 4; ++r) {
                acc[tb][r] += b;
                sq[r] += acc[tb][r] * acc[tb][r];
            }
        }
#pragma unroll
        for (int r = 0; r < 4; ++r) part[wv * 16 + lq * 4 + r][lm] = sq[r];
        __syncthreads();
        if (t < 64) {
            float s = 0.f;
#pragma unroll
            for (int c = 0; c < 16; ++c) s += part[t][c];
            rinv[t] = 1.0f / fmaxf(sqrtf(s), 1e-12f);
        }
        __syncthreads();
#pragma unroll
        for (int r = 0; r < 4; ++r) {
            int gr = m0 + wv * 16 + lq * 4 + r;
            if (gr >= M) continue;
            float ri = rinv[wv * 16 + lq * 4 + r];
#pragma unroll
            for (int tb = 0; tb < 8; ++tb) {
                int col = tb * 16 + lm;
                float o = bfs(residbf[(size_t)gr * 128 + col]) +
                          fmaxf(acc[tb][r], 0.f) * ri;
                Cbf[(size_t)gr * 128 + col] = f2bf(o);
            }
        }
    } else {
#pragma unroll
        for (int r = 0; r < 4; ++r) {
            int gr = m0 + wv * 16 + lq * 4 + r;
            if (gr >= M) continue;
#pragma unroll
            for (int tb = 0; tb < 8; ++tb) {
                int col = tb * 16 + lm;
                float v = acc[tb][r] + bs[col];
                Cbf[(size_t)gr * ldc + col] =
                    (EPI == EPI_PQH) ? f2h(v) : f2bf(v);
            }
        }
    }
}

// ---------------------------------------------------------------------------
// x -> bf16 cast (embed input)
// ---------------------------------------------------------------------------
__global__ void cast_k(const float* __restrict__ x, unsigned short* __restrict__ xbf,
                       int n8) {
    int i = blockIdx.x * 256 + threadIdx.x;
    if (i >= n8) return;
    float4 a = *(const float4*)&x[(size_t)i * 8];
    float4 b = *(const float4*)&x[(size_t)i * 8 + 4];
    uint4 o = make_uint4(packbf(a.x, a.y), packbf(a.z, a.w),
                         packbf(b.x, b.y), packbf(b.z, b.w));
    *(uint4*)&xbf[(size_t)i * 8] = o;
}

// ---------------------------------------------------------------------------
// CSR construction. deg_k records each edge's slot (ofs[e] = atomicAdd
// return, coalesced write) so fill_k needs NO atomics.
// ---------------------------------------------------------------------------
__global__ void deg_k(const int* __restrict__ dst, int* __restrict__ deg,
                      int* __restrict__ ofs) {
    int e = blockIdx.x * 256 + threadIdx.x;
    if (e < NE) ofs[e] = atomicAdd(&deg[dst[e]], 1);
}

__global__ void scan1_k(const int* __restrict__ deg, int* __restrict__ rp,
                        int* __restrict__ bsum) {
    __shared__ int sh[512];
    int tid = threadIdx.x;
    int i = blockIdx.x * 512 + tid;
    int v = (i < NN) ? deg[i] : 0;
    sh[tid] = v;
    __syncthreads();
    for (int ofs = 1; ofs < 512; ofs <<= 1) {
        int x = (tid >= ofs) ? sh[tid - ofs] : 0;
        __syncthreads();
        sh[tid] += x;
        __syncthreads();
    }
    if (i < NN) rp[i] = sh[tid] - v;
    if (tid == 511) bsum[blockIdx.x] = sh[511];
}

__global__ void scan2_k(int* __restrict__ bsum, int nb) {
    __shared__ int sh[128];
    int tid = threadIdx.x;
    int v = (tid < nb) ? bsum[tid] : 0;
    sh[tid] = v;
    __syncthreads();
    for (int ofs = 1; ofs < 128; ofs <<= 1) {
        int x = (tid >= ofs) ? sh[tid - ofs] : 0;
        __syncthreads();
        sh[tid] += x;
        __syncthreads();
    }
    if (tid < nb) bsum[tid] = sh[tid] - v;
}

__global__ void scan3_k(int* __restrict__ rp, const int* __restrict__ bsum,
                        const int* __restrict__ deg, float* __restrict__ invd) {
    int i = blockIdx.x * 512 + threadIdx.x;
    if (i < NN) {
        rp[i] += bsum[blockIdx.x];
        int d = deg[i];
        invd[i] = 1.0f / (float)(d > 1 ? d : 1);
    }
    if (i == NN) rp[NN] = NE;
}

// atomic-free fill: pos = rp[dst] + ofs[e]; 12B scatter (srt 4B + de 8B)
__global__ void fill_k(const int* __restrict__ src, const int* __restrict__ dst,
                       const int* __restrict__ rp, const int* __restrict__ ofs,
                       int* __restrict__ srt, int2* __restrict__ de) {
    int e = blockIdx.x * 256 + threadIdx.x;
    if (e < NE) {
        int d = dst[e];
        int pos = rp[d] + ofs[e];
        srt[pos] = src[e];
        de[pos]  = make_int2(d, e);
    }
}

// ---------------------------------------------------------------------------
// Mean aggregation, one WAVE per node. Lane layout: 32 lanes x 8 B per row,
// wave halves process alternating neighbor rows => 1 VMEM instr / 2 rows,
// 4-pair unroll => 8 rows in flight. Halves combined via shfl_xor(32).
// ---------------------------------------------------------------------------
__launch_bounds__(256, 8)
__global__ void agg_k(const unsigned short* __restrict__ hbf,
                      const int* __restrict__ rp, const int* __restrict__ srt,
                      const float* __restrict__ invd,
                      unsigned short* __restrict__ cbf) {
    int gw   = (blockIdx.x * 256 + threadIdx.x) >> 6;   // node = global wave id
    if (gw >= NN) return;
    const int lane = threadIdx.x & 63;
    const int half = lane >> 5;          // which neighbor of the pair
    const int hl   = lane & 31;          // feature group: 4 feats (8 B)
    const int b = rp[gw], e = rp[gw + 1];
    float a0 = 0.f, a1 = 0.f, a2 = 0.f, a3 = 0.f;

    int p = b;
    for (; p + 8 <= e; p += 8) {         // 4 pairs, 8 rows in flight
        int s0 = srt[p     + half];
        int s1 = srt[p + 2 + half];
        int s2 = srt[p + 4 + half];
        int s3 = srt[p + 6 + half];
        uint2 u0 = *(const uint2*)&hbf[(size_t)s0 * 128 + hl * 4];
        uint2 u1 = *(const uint2*)&hbf[(size_t)s1 * 128 + hl * 4];
        uint2 u2 = *(const uint2*)&hbf[(size_t)s2 * 128 + hl * 4];
        uint2 u3 = *(const uint2*)&hbf[(size_t)s3 * 128 + hl * 4];
        a0 += bflo(u0.x) + bflo(u1.x) + bflo(u2.x) + bflo(u3.x);
        a1 += bfhi(u0.x) + bfhi(u1.x) + bfhi(u2.x) + bfhi(u3.x);
        a2 += bflo(u0.y) + bflo(u1.y) + bflo(u2.y) + bflo(u3.y);
        a3 += bfhi(u0.y) + bfhi(u1.y) + bfhi(u2.y) + bfhi(u3.y);
    }
    for (; p + 2 <= e; p += 2) {         // single pair
        int s = srt[p + half];
        uint2 u = *(const uint2*)&hbf[(size_t)s * 128 + hl * 4];
        a0 += bflo(u.x); a1 += bfhi(u.x);
        a2 += bflo(u.y); a3 += bfhi(u.y);
    }
    if (p < e && half == 0) {            // odd-degree tail (half 0 only)
        int s = srt[p];
        uint2 u = *(const uint2*)&hbf[(size_t)s * 128 + hl * 4];
        a0 += bflo(u.x); a1 += bfhi(u.x);
        a2 += bflo(u.y); a3 += bfhi(u.y);
    }
    // combine halves
    a0 += __shfl_xor(a0, 32, 64);
    a1 += __shfl_xor(a1, 32, 64);
    a2 += __shfl_xor(a2, 32, 64);
    a3 += __shfl_xor(a3, 32, 64);

    float iv = invd[gw];
    if (half == 0) {
        uint2 r = make_uint2(packbf(a0 * iv, a1 * iv), packbf(a2 * iv, a3 * iv));
        *(uint2*)&cbf[(size_t)gw * 128 + hl * 4] = r;
    }
}

// ---------------------------------------------------------------------------
// Prep: Wct[4][128n][256k] bf16; Wefft[256n][128k] bf16; W1tg[64n][128k] FP16;
// beff; Wembt bf16.
// ---------------------------------------------------------------------------
__global__ void prep_k(const float* __restrict__ Wconv, const float* __restrict__ W0,
                       const float* __restrict__ b0, const float* __restrict__ W1,
                       const float* __restrict__ Wemb,
                       unsigned short* __restrict__ Wct,
                       unsigned short* __restrict__ Wefft,
                       float* __restrict__ beff, unsigned short* __restrict__ W1tg,
                       unsigned short* __restrict__ Wembt) {
    int i = blockIdx.x * 256 + threadIdx.x;
    if (i < 131072) {
        int lyr = i >> 15, r = i & 32767, n = r >> 8, k = r & 255;
        Wct[i] = f2bf(Wconv[(size_t)lyr * 32768 + k * 128 + n]);
    } else if (i < 163840) {
        int j = i - 131072, n = j >> 7, k = j & 127;
        float v = (n < 128) ? W0[k * 128 + n] : W0[(128 + k) * 128 + (n - 128)];
        Wefft[j] = f2bf(v);
    } else if (i < 172032) {
        int j = i - 163840, n = j >> 7, k = j & 127;
        W1tg[j] = f2h(W1[k * 64 + n]);                 // fp16 for edge MFMA
    } else if (i < 172288) {
        int j = i - 172032;
        beff[j] = (j < 128) ? b0[j] : 0.f;
    } else if (i < 180480) {
        int j = i - 172288, n = j >> 6, k = j & 63;
        Wembt[j] = f2bf(Wemb[k * 128 + n]);
    }
}

// ---------------------------------------------------------------------------
// Fused edge readout (fp16 MFMA), CSR order, 128 edges/block, 512 threads,
// single barrier, in-register MLP2 (shfl reduce).
// LDS tiles are LINEAR [*][128] with 16B-chunk XOR swizzle (chunk ^= row&7):
// each 8-lane quarter-group of the MFMA frag reads covers all 8 128B-phases
// -> bank-conflict-free (was 5.6M conflict cycles with the padded layout).
// ---------------------------------------------------------------------------
__launch_bounds__(512, 6)
__global__ void edge_mlp_k(const unsigned short* __restrict__ pq,   // fp16 [NN][256]
                           const int* __restrict__ srt,
                           const int2* __restrict__ de,
                           const unsigned short* __restrict__ W1tg, // fp16 [64][128]
                           const float* __restrict__ b1,
                           const float* __restrict__ W2, const float* __restrict__ b2,
                           float* __restrict__ out)
{
    __shared__ __align__(16) unsigned short E0s[128][128];  // fp16, 32 KB
    __shared__ __align__(16) unsigned short W1s[64][128];   // fp16, 16 KB
    __shared__ int ee[128];
    const int t = threadIdx.x;
    const int p0 = blockIdx.x * 128;

    // stage W1 (swizzled): 64 rows x 128 fp16 = 1024 uint4 (2 per thread)
#pragma unroll
    for (int p = 0; p < 2; ++p) {
        int i4 = p * 512 + t;                 // 0..1023
        int row = i4 >> 4;                    // 0..63
        int c4  = i4 & 15;                    // 16B chunk within row
        *(uint4*)&W1s[row][(c4 ^ (row & 7)) * 8] = ((const uint4*)W1tg)[i4];
    }

    // phase 1: e0 = relu(p[src] + q[dst]) packed fp16 -> E0s (4 threads/edge)
    {
        const int ei = t >> 2;                // 0..127
        const int cb = t & 3;                 // chunk group: chunks cb*4+j
        const int fs = cb * 32;
        int  sv  = srt[p0 + ei];
        int2 dev = de[p0 + ei];
        if (cb == 0) ee[ei] = dev.y;
        const unsigned short* pr = pq + (size_t)sv * 256 + fs;
        const unsigned short* qr = pq + (size_t)dev.x * 256 + 128 + fs;
#pragma unroll
        for (int j = 0; j < 4; ++j) {
            uint4 a = *(const uint4*)(pr + j * 8);
            uint4 b = *(const uint4*)(qr + j * 8);
            uint4 r = make_uint4(pk_add_relu(a.x, b.x), pk_add_relu(a.y, b.y),
                                 pk_add_relu(a.z, b.z), pk_add_relu(a.w, b.w));
            *(uint4*)&E0s[ei][((cb * 4 + j) ^ (ei & 7)) * 8] = r;
        }
    }
    __syncthreads();                 // single barrier

    // phase 2: fp16 MFMA. wave wv: edges [16wv,16wv+16) x 64 outs.
    const int wv = t >> 6, l = t & 63, lq = l >> 4, lm = l & 15;
    frag_cd acc[4];
#pragma unroll
    for (int tb = 0; tb < 4; ++tb) acc[tb] = (frag_cd){0.f, 0.f, 0.f, 0.f};
    const int erow = wv * 16 + lm;
#pragma unroll
    for (int kb = 0; kb < 4; ++kb) {
        const int ca = kb * 4 + lq;
        frag_h af = *(const frag_h*)&E0s[erow][(ca ^ (erow & 7)) * 8];
#pragma unroll
        for (int tb = 0; tb < 4; ++tb) {
            const int rw = tb * 16 + lm;
            frag_h bf = *(const frag_h*)&W1s[rw][(ca ^ (rw & 7)) * 8];
            acc[tb] = __builtin_amdgcn_mfma_f32_16x16x32_f16(af, bf, acc[tb], 0, 0, 0);
        }
    }

    // phase 3: in-register MLP2 (b1/W2 direct from global, L2-resident)
    float b1v[4], w20[4], w21[4];
#pragma unroll
    for (int tb = 0; tb < 4; ++tb) {
        int o = tb * 16 + lm;
        b1v[tb] = b1[o];
        w20[tb] = W2[o * 2];
        w21[tb] = W2[o * 2 + 1];
    }
    const float bo0 = b2[0], bo1 = b2[1];
#pragma unroll
    for (int r = 0; r < 4; ++r) {
        float s0 = 0.f, s1 = 0.f;
#pragma unroll
        for (int tb = 0; tb < 4; ++tb) {
            float e1 = fmaxf(acc[tb][r] + b1v[tb], 0.f);
            s0 += e1 * w20[tb];
            s1 += e1 * w21[tb];
        }
#pragma unroll
        for (int m = 1; m < 16; m <<= 1) {   // reduce over lm
            s0 += __shfl_xor(s0, m, 16);
            s1 += __shfl_xor(s1, m, 16);
        }
        if (lm == 0) {
            int e = wv * 16 + lq * 4 + r;    // 0..127
            *(float2*)&out[(size_t)ee[e] * 2] = make_float2(s0 + bo0, s1 + bo1);
        }
    }
}

// ---------------------------------------------------------------------------
extern "C" void kernel_launch(void* const* d_in, const int* in_sizes, int n_in,
                              void* d_out, int out_size, void* d_ws, size_t ws_size,
                              hipStream_t stream)
{
    const float* x    = (const float*)d_in[0];
    const int*   esrc = (const int*)  d_in[1];
    const int*   edst = (const int*)  d_in[2];
    const float* Wemb  = (const float*)d_in[5];
    const float* bemb  = (const float*)d_in[6];
    const float* Wconv = (const float*)d_in[7];
    const float* bconv = (const float*)d_in[8];
    const float* Wm0   = (const float*)d_in[9];
    const float* bm0   = (const float*)d_in[10];
    const float* Wm1   = (const float*)d_in[11];
    const float* bm1   = (const float*)d_in[12];
    const float* Wm2   = (const float*)d_in[13];
    const float* bm2   = (const float*)d_in[14];
    float* out = (float*)d_out;

    char* ws = (char*)d_ws;
    size_t off = 0;
    auto alloc = [&](size_t bytes) -> void* {
        void* p = ws + off;
        off = (off + bytes + 255) & ~(size_t)255;
        return p;
    };
    unsigned short* h0bf = (unsigned short*)alloc((size_t)NN * 128 * 2);
    unsigned short* h1bf = (unsigned short*)alloc((size_t)NN * 128 * 2);
    unsigned short* cbf  = (unsigned short*)alloc((size_t)NN * 128 * 2);
    unsigned short* pqb  = (unsigned short*)alloc((size_t)NN * 256 * 2);
    unsigned short* xbf  = (unsigned short*)alloc((size_t)NN * 64 * 2);
    unsigned short* Wct   = (unsigned short*)alloc(4 * 128 * 256 * 2);
    unsigned short* Wefft = (unsigned short*)alloc(256 * 128 * 2);
    float*          beff  = (float*)alloc(256 * 4);
    unsigned short* W1tg  = (unsigned short*)alloc(64 * 128 * 2);
    unsigned short* Wembt = (unsigned short*)alloc(128 * 64 * 2);
    int*   deg  = (int*)alloc((size_t)NN * 4);
    int*   rp   = (int*)alloc((size_t)(NN + 1) * 4);
    float* invd = (float*)alloc((size_t)NN * 4);
    int*   bsum = (int*)alloc(512);
    int*   ofs  = (int*)alloc((size_t)NE * 4);
    int*   srt  = (int*)alloc((size_t)NE * 4);
    int2*  de   = (int2*)alloc((size_t)NE * 8);
    (void)ws_size; (void)in_sizes; (void)n_in; (void)out_size;

    hipMemsetAsync(deg, 0, (size_t)NN * 4, stream);

    // cast x -> bf16; weight prep
    cast_k<<<(NN * 64 / 8 + 255) / 256, 256, 0, stream>>>(x, xbf, NN * 64 / 8);
    prep_k<<<(180480 + 255) / 256, 256, 0, stream>>>(
        Wconv, Wm0, bm0, Wm1, Wemb, Wct, Wefft, beff, W1tg, Wembt);

    // CSR build: deg (+per-edge slot), scan, atomic-free fill
    deg_k  <<<(NE + 255) / 256, 256, 0, stream>>>(edst, deg, ofs);
    scan1_k<<<(NN + 511) / 512, 512, 0, stream>>>(deg, rp, bsum);
    scan2_k<<<1, 128, 0, stream>>>(bsum, (NN + 511) / 512);
    scan3_k<<<(NN + 511) / 512, 512, 0, stream>>>(rp, bsum, deg, invd);
    fill_k <<<(NE + 255) / 256, 256, 0, stream>>>(esrc, edst, rp, ofs, srt, de);

    // h0 = bf16(x @ Wemb + bemb) via MFMA
    mfma_gemm_k<EPI_PQBF><<<dim3((NN + 63) / 64, 1), 256, 0, stream>>>(
        xbf, nullptr, 64, 1 << 30, Wembt, bemb, h0bf, 128, nullptr, NN, 64);

    // 4 SAGE layers (MFMA, bf16 residual)
    unsigned short* hcbf = h0bf; unsigned short* hnbf = h1bf;
    for (int l = 0; l < 4; ++l) {
        agg_k<<<(NN + 3) / 4, 256, 0, stream>>>(hcbf, rp, srt, invd, cbf);
        mfma_gemm_k<EPI_LAYER><<<dim3((NN + 63) / 64, 1), 256, 0, stream>>>(
            hcbf, cbf, 128, 128, Wct + (size_t)l * 128 * 256,
            bconv + (size_t)l * 128, hnbf, 128, hcbf, NN, 256);
        unsigned short* tb = hcbf; hcbf = hnbf; hnbf = tb;
    }
    // after 4 layers: hcbf == h0bf

    // pq = fp16(h @ Weff + beff)  [NN][256]  (fp16 feeds edge pipeline)
    mfma_gemm_k<EPI_PQH><<<dim3((NN + 63) / 64, 2), 256, 0, stream>>>(
        hcbf, nullptr, 128, 1 << 30, Wefft, beff, pqb, 256, nullptr, NN, 128);

    // fused edge readout (CSR order, 128 edges/block, single barrier)
    edge_mlp_k<<<NE / 128, 512, 0, stream>>>(pqb, srt, de, W1tg, bm1, Wm2, bm2, out);
}

// Round 7
// 420.867 us; speedup vs baseline: 1.2794x; 1.0233x over previous
//
#include <hip/hip_runtime.h>

constexpr int NN  = 50000;   // nodes
constexpr int NE  = 800000;  // edges

using frag_ab = __attribute__((ext_vector_type(8))) short;     // 8 bf16
using frag_h  = __attribute__((ext_vector_type(8))) _Float16;  // 8 fp16
using frag_cd = __attribute__((ext_vector_type(4))) float;     // 4 fp32
using h2      = __attribute__((ext_vector_type(2))) _Float16;  // 2 fp16

__device__ __forceinline__ unsigned short f2bf(float f) {   // RNE
    union { float f; unsigned u; } v; v.f = f;
    unsigned r = v.u + 0x7FFFu + ((v.u >> 16) & 1u);
    return (unsigned short)(r >> 16);
}
__device__ __forceinline__ unsigned short f2h(float f) {    // RNE via HW cvt
    union { _Float16 h; unsigned short u; } v; v.h = (_Float16)f; return v.u;
}
__device__ __forceinline__ float bflo(unsigned u) {
    union { unsigned u; float f; } v; v.u = u << 16; return v.f;
}
__device__ __forceinline__ float bfhi(unsigned u) {
    union { unsigned u; float f; } v; v.u = u & 0xFFFF0000u; return v.f;
}
__device__ __forceinline__ float bfs(unsigned short u) {
    union { unsigned u; float f; } v; v.u = (unsigned)u << 16; return v.f;
}
__device__ __forceinline__ unsigned packbf(float a, float b) {       // RNE
    return (unsigned)f2bf(a) | ((unsigned)f2bf(b) << 16);
}
// packed fp16 relu(a+b): clang lowers to v_pk_add_f16 + v_pk_max_f16 (2 VALU ops)
__device__ __forceinline__ unsigned pk_add_relu(unsigned a, unsigned b) {
    union Cu { unsigned u; h2 h; };
    Cu ua; ua.u = a;
    Cu ub; ub.u = b;
    h2 s = ua.h + ub.h;
    h2 z; z[0] = (_Float16)0.f; z[1] = (_Float16)0.f;
    Cu r; r.h = __builtin_elementwise_max(s, z);
    return r.u;
}

// global -> LDS direct DMA, 16 B/lane. LDS dest = wave-uniform base + lane*16
// (m104); global src is per-lane. Literal size arg required.
__device__ __forceinline__ void gload_lds16(const unsigned short* g,
                                            unsigned short* l) {
    __builtin_amdgcn_global_load_lds(
        (const __attribute__((address_space(1))) unsigned int*)g,
        (__attribute__((address_space(3))) unsigned int*)l, 16, 0, 0);
}

enum { EPI_LAYER = 1, EPI_PQBF = 2, EPI_PQH = 3 };

// ---------------------------------------------------------------------------
// MFMA bf16 GEMM. Block: 64 rows x 128 cols, 4 waves, BK=64.
// Staging via global_load_lds (linear LDS, no pad). Tail rows (gm >= M) read
// garbage from adjacent workspace -- harmless: MFMA row i only affects output
// row i, and rows >= M are never stored.
// EPI_PQH writes fp16 output (feeds the fp16 edge pipeline).
// ---------------------------------------------------------------------------
template<int EPI>
__launch_bounds__(256, 4)
__global__ void mfma_gemm_k(const unsigned short* __restrict__ A0,
                            const unsigned short* __restrict__ A1,
                            int lda, int kSplit,
                            const unsigned short* __restrict__ Wt,
                            const float* __restrict__ bias,
                            unsigned short* __restrict__ Cbf, int ldc,
                            const unsigned short* __restrict__ residbf,
                            int M, int K)
{
    __shared__ __align__(16) unsigned short As[64][64];    // 8 KB, linear
    __shared__ __align__(16) unsigned short Ws[128][64];   // 16 KB, linear
    __shared__ float bs[128];
    __shared__ float part[(EPI == EPI_LAYER) ? 64 : 1][17];
    __shared__ float rinv[(EPI == EPI_LAYER) ? 64 : 1];

    const int t  = threadIdx.x;
    const int by = blockIdx.y;
    Wt   += (size_t)by * 128 * K;
    bias += (size_t)by * 128;
    if constexpr (EPI != EPI_LAYER) Cbf += (size_t)by * 128;
    const int m0 = blockIdx.x * 64;

    if (t < 128) bs[t] = bias[t];

    const int wv = t >> 6, l = t & 63, lq = l >> 4, lm = l & 15;
    const int sr = l >> 3;            // staging: row within 8-row group
    const int sc = (l & 7) * 8;       // staging: col element offset (16 B)
    frag_cd acc[8];
#pragma unroll
    for (int tb = 0; tb < 8; ++tb) acc[tb] = (frag_cd){0.f, 0.f, 0.f, 0.f};

    for (int kt = 0; kt < K; kt += 64) {
        const unsigned short* Asrc = (kt < kSplit) ? A0 : A1;
        const int kcol = (kt < kSplit) ? kt : kt - kSplit;
        // A tile 64x64: wave wv stages rows [16wv,16wv+16), 2 DMA x 8 rows
#pragma unroll
        for (int i = 0; i < 2; ++i) {
            int row = wv * 16 + i * 8;
            int gm  = m0 + row + sr;
            gload_lds16(&Asrc[(size_t)gm * lda + kcol + sc], &As[row][0]);
        }
        // W tile 128x64: wave wv stages rows [32wv,32wv+32), 4 DMA x 8 rows
#pragma unroll
        for (int i = 0; i < 4; ++i) {
            int row = wv * 32 + i * 8;
            int n   = row + sr;
            gload_lds16(&Wt[(size_t)n * K + kt + sc], &Ws[row][0]);
        }
        __syncthreads();
#pragma unroll
        for (int kb = 0; kb < 2; ++kb) {
            frag_ab af = *(const frag_ab*)&As[wv * 16 + lm][kb * 32 + lq * 8];
#pragma unroll
            for (int tb = 0; tb < 8; ++tb) {
                frag_ab bf = *(const frag_ab*)&Ws[tb * 16 + lm][kb * 32 + lq * 8];
                acc[tb] = __builtin_amdgcn_mfma_f32_16x16x32_bf16(af, bf, acc[tb], 0, 0, 0);
            }
        }
        __syncthreads();
    }

    if constexpr (EPI == EPI_LAYER) {
        float sq[4] = {0.f, 0.f, 0.f, 0.f};
#pragma unroll
        for (int tb = 0; tb < 8; ++tb) {
            float b = bs[tb * 16 + lm];
#pragma unroll
            for (int r = 0; r < 4; ++r) {
                acc[tb][r] += b;
                sq[r] += acc[tb][r] * acc[tb][r];
            }
        }
#pragma unroll
        for (int r = 0; r < 4; ++r) part[wv * 16 + lq * 4 + r][lm] = sq[r];
        __syncthreads();
        if (t < 64) {
            float s = 0.f;
#pragma unroll
            for (int c = 0; c < 16; ++c) s += part[t][c];
            rinv[t] = 1.0f / fmaxf(sqrtf(s), 1e-12f);
        }
        __syncthreads();
#pragma unroll
        for (int r = 0; r < 4; ++r) {
            int gr = m0 + wv * 16 + lq * 4 + r;
            if (gr >= M) continue;
            float ri = rinv[wv * 16 + lq * 4 + r];
#pragma unroll
            for (int tb = 0; tb < 8; ++tb) {
                int col = tb * 16 + lm;
                float o = bfs(residbf[(size_t)gr * 128 + col]) +
                          fmaxf(acc[tb][r], 0.f) * ri;
                Cbf[(size_t)gr * 128 + col] = f2bf(o);
            }
        }
    } else {
#pragma unroll
        for (int r = 0; r < 4; ++r) {
            int gr = m0 + wv * 16 + lq * 4 + r;
            if (gr >= M) continue;
#pragma unroll
            for (int tb = 0; tb < 8; ++tb) {
                int col = tb * 16 + lm;
                float v = acc[tb][r] + bs[col];
                Cbf[(size_t)gr * ldc + col] =
                    (EPI == EPI_PQH) ? f2h(v) : f2bf(v);
            }
        }
    }
}

// ---------------------------------------------------------------------------
// x -> bf16 cast (embed input)
// ---------------------------------------------------------------------------
__global__ void cast_k(const float* __restrict__ x, unsigned short* __restrict__ xbf,
                       int n8) {
    int i = blockIdx.x * 256 + threadIdx.x;
    if (i >= n8) return;
    float4 a = *(const float4*)&x[(size_t)i * 8];
    float4 b = *(const float4*)&x[(size_t)i * 8 + 4];
    uint4 o = make_uint4(packbf(a.x, a.y), packbf(a.z, a.w),
                         packbf(b.x, b.y), packbf(b.z, b.w));
    *(uint4*)&xbf[(size_t)i * 8] = o;
}

// ---------------------------------------------------------------------------
// CSR construction. deg_k records each edge's slot (ofs[e] = atomicAdd
// return, coalesced write) so fill_k needs NO atomics.
// ---------------------------------------------------------------------------
__global__ void deg_k(const int* __restrict__ dst, int* __restrict__ deg,
                      int* __restrict__ ofs) {
    int e = blockIdx.x * 256 + threadIdx.x;
    if (e < NE) ofs[e] = atomicAdd(&deg[dst[e]], 1);
}

__global__ void scan1_k(const int* __restrict__ deg, int* __restrict__ rp,
                        int* __restrict__ bsum) {
    __shared__ int sh[512];
    int tid = threadIdx.x;
    int i = blockIdx.x * 512 + tid;
    int v = (i < NN) ? deg[i] : 0;
    sh[tid] = v;
    __syncthreads();
    for (int ofs = 1; ofs < 512; ofs <<= 1) {
        int x = (tid >= ofs) ? sh[tid - ofs] : 0;
        __syncthreads();
        sh[tid] += x;
        __syncthreads();
    }
    if (i < NN) rp[i] = sh[tid] - v;
    if (tid == 511) bsum[blockIdx.x] = sh[511];
}

__global__ void scan2_k(int* __restrict__ bsum, int nb) {
    __shared__ int sh[128];
    int tid = threadIdx.x;
    int v = (tid < nb) ? bsum[tid] : 0;
    sh[tid] = v;
    __syncthreads();
    for (int ofs = 1; ofs < 128; ofs <<= 1) {
        int x = (tid >= ofs) ? sh[tid - ofs] : 0;
        __syncthreads();
        sh[tid] += x;
        __syncthreads();
    }
    if (tid < nb) bsum[tid] = sh[tid] - v;
}

__global__ void scan3_k(int* __restrict__ rp, const int* __restrict__ bsum,
                        const int* __restrict__ deg, float* __restrict__ invd) {
    int i = blockIdx.x * 512 + threadIdx.x;
    if (i < NN) {
        rp[i] += bsum[blockIdx.x];
        int d = deg[i];
        invd[i] = 1.0f / (float)(d > 1 ? d : 1);
    }
    if (i == NN) rp[NN] = NE;
}

// atomic-free fill: pos = rp[dst] + ofs[e]; 12B scatter (srt 4B + de 8B)
__global__ void fill_k(const int* __restrict__ src, const int* __restrict__ dst,
                       const int* __restrict__ rp, const int* __restrict__ ofs,
                       int* __restrict__ srt, int2* __restrict__ de) {
    int e = blockIdx.x * 256 + threadIdx.x;
    if (e < NE) {
        int d = dst[e];
        int pos = rp[d] + ofs[e];
        srt[pos] = src[e];
        de[pos]  = make_int2(d, e);
    }
}

// ---------------------------------------------------------------------------
// Mean aggregation, one WAVE per node, 16B/lane loads: 16 lanes cover one
// 256B row, one VMEM instr gathers 4 rows (vs 2 with 8B/lane) -> half the
// VMEM issue + address VALU per row. 8 accumulators/lane; quarter-wave
// reduction via shfl_xor(16)+shfl_xor(32); quarter 0 writes the row.
// ---------------------------------------------------------------------------
__launch_bounds__(256, 8)
__global__ void agg_k(const unsigned short* __restrict__ hbf,
                      const int* __restrict__ rp, const int* __restrict__ srt,
                      const float* __restrict__ invd,
                      unsigned short* __restrict__ cbf) {
    int gw   = (blockIdx.x * 256 + threadIdx.x) >> 6;   // node = global wave id
    if (gw >= NN) return;
    const int lane = threadIdx.x & 63;
    const int q  = lane >> 4;            // quarter: neighbor offset within group
    const int hq = lane & 15;            // 16B chunk: features [hq*8, hq*8+8)
    const int b = rp[gw], e = rp[gw + 1];
    float a0 = 0.f, a1 = 0.f, a2 = 0.f, a3 = 0.f;
    float a4 = 0.f, a5 = 0.f, a6 = 0.f, a7 = 0.f;

    int p = b;
    for (; p + 8 <= e; p += 8) {         // 2 loads, 8 rows in flight
        int s0 = srt[p     + q];
        int s1 = srt[p + 4 + q];
        uint4 u0 = *(const uint4*)&hbf[(size_t)s0 * 128 + hq * 8];
        uint4 u1 = *(const uint4*)&hbf[(size_t)s1 * 128 + hq * 8];
        a0 += bflo(u0.x) + bflo(u1.x);  a1 += bfhi(u0.x) + bfhi(u1.x);
        a2 += bflo(u0.y) + bflo(u1.y);  a3 += bfhi(u0.y) + bfhi(u1.y);
        a4 += bflo(u0.z) + bflo(u1.z);  a5 += bfhi(u0.z) + bfhi(u1.z);
        a6 += bflo(u0.w) + bflo(u1.w);  a7 += bfhi(u0.w) + bfhi(u1.w);
    }
    for (; p + 4 <= e; p += 4) {         // single 4-row load
        int s = srt[p + q];
        uint4 u = *(const uint4*)&hbf[(size_t)s * 128 + hq * 8];
        a0 += bflo(u.x);  a1 += bfhi(u.x);
        a2 += bflo(u.y);  a3 += bfhi(u.y);
        a4 += bflo(u.z);  a5 += bfhi(u.z);
        a6 += bflo(u.w);  a7 += bfhi(u.w);
    }
    if (p + q < e) {                     // tail 1..3 rows: quarters q < rem
        int s = srt[p + q];
        uint4 u = *(const uint4*)&hbf[(size_t)s * 128 + hq * 8];
        a0 += bflo(u.x);  a1 += bfhi(u.x);
        a2 += bflo(u.y);  a3 += bfhi(u.y);
        a4 += bflo(u.z);  a5 += bfhi(u.z);
        a6 += bflo(u.w);  a7 += bfhi(u.w);
    }
    // reduce across quarters (lanes {l, l^16, l^32, l^48} share hq)
    a0 += __shfl_xor(a0, 16, 64); a0 += __shfl_xor(a0, 32, 64);
    a1 += __shfl_xor(a1, 16, 64); a1 += __shfl_xor(a1, 32, 64);
    a2 += __shfl_xor(a2, 16, 64); a2 += __shfl_xor(a2, 32, 64);
    a3 += __shfl_xor(a3, 16, 64); a3 += __shfl_xor(a3, 32, 64);
    a4 += __shfl_xor(a4, 16, 64); a4 += __shfl_xor(a4, 32, 64);
    a5 += __shfl_xor(a5, 16, 64); a5 += __shfl_xor(a5, 32, 64);
    a6 += __shfl_xor(a6, 16, 64); a6 += __shfl_xor(a6, 32, 64);
    a7 += __shfl_xor(a7, 16, 64); a7 += __shfl_xor(a7, 32, 64);

    float iv = invd[gw];
    if (q == 0) {
        uint4 r = make_uint4(packbf(a0 * iv, a1 * iv), packbf(a2 * iv, a3 * iv),
                             packbf(a4 * iv, a5 * iv), packbf(a6 * iv, a7 * iv));
        *(uint4*)&cbf[(size_t)gw * 128 + hq * 8] = r;
    }
}

// ---------------------------------------------------------------------------
// Prep: Wct[4][128n][256k] bf16; Wefft[256n][128k] bf16; W1tg[64n][128k] FP16;
// beff; Wembt bf16.
// ---------------------------------------------------------------------------
__global__ void prep_k(const float* __restrict__ Wconv, const float* __restrict__ W0,
                       const float* __restrict__ b0, const float* __restrict__ W1,
                       const float* __restrict__ Wemb,
                       unsigned short* __restrict__ Wct,
                       unsigned short* __restrict__ Wefft,
                       float* __restrict__ beff, unsigned short* __restrict__ W1tg,
                       unsigned short* __restrict__ Wembt) {
    int i = blockIdx.x * 256 + threadIdx.x;
    if (i < 131072) {
        int lyr = i >> 15, r = i & 32767, n = r >> 8, k = r & 255;
        Wct[i] = f2bf(Wconv[(size_t)lyr * 32768 + k * 128 + n]);
    } else if (i < 163840) {
        int j = i - 131072, n = j >> 7, k = j & 127;
        float v = (n < 128) ? W0[k * 128 + n] : W0[(128 + k) * 128 + (n - 128)];
        Wefft[j] = f2bf(v);
    } else if (i < 172032) {
        int j = i - 163840, n = j >> 7, k = j & 127;
        W1tg[j] = f2h(W1[k * 64 + n]);                 // fp16 for edge MFMA
    } else if (i < 172288) {
        int j = i - 172032;
        beff[j] = (j < 128) ? b0[j] : 0.f;
    } else if (i < 180480) {
        int j = i - 172288, n = j >> 6, k = j & 63;
        Wembt[j] = f2bf(Wemb[k * 128 + n]);
    }
}

// ---------------------------------------------------------------------------
// Fused edge readout (fp16 MFMA), CSR order, 128 edges/block, 512 threads,
// single barrier, in-register MLP2 (shfl reduce). LDS linear [*][128] with
// 16B-chunk XOR swizzle (chunk ^= row&7).
// ---------------------------------------------------------------------------
__launch_bounds__(512, 6)
__global__ void edge_mlp_k(const unsigned short* __restrict__ pq,   // fp16 [NN][256]
                           const int* __restrict__ srt,
                           const int2* __restrict__ de,
                           const unsigned short* __restrict__ W1tg, // fp16 [64][128]
                           const float* __restrict__ b1,
                           const float* __restrict__ W2, const float* __restrict__ b2,
                           float* __restrict__ out)
{
    __shared__ __align__(16) unsigned short E0s[128][128];  // fp16, 32 KB
    __shared__ __align__(16) unsigned short W1s[64][128];   // fp16, 16 KB
    __shared__ int ee[128];
    const int t = threadIdx.x;
    const int p0 = blockIdx.x * 128;

    // stage W1 (swizzled): 64 rows x 128 fp16 = 1024 uint4 (2 per thread)
#pragma unroll
    for (int p = 0; p < 2; ++p) {
        int i4 = p * 512 + t;                 // 0..1023
        int row = i4 >> 4;                    // 0..63
        int c4  = i4 & 15;                    // 16B chunk within row
        *(uint4*)&W1s[row][(c4 ^ (row & 7)) * 8] = ((const uint4*)W1tg)[i4];
    }

    // phase 1: e0 = relu(p[src] + q[dst]) packed fp16 -> E0s (4 threads/edge)
    {
        const int ei = t >> 2;                // 0..127
        const int cb = t & 3;                 // chunk group: chunks cb*4+j
        const int fs = cb * 32;
        int  sv  = srt[p0 + ei];
        int2 dev = de[p0 + ei];
        if (cb == 0) ee[ei] = dev.y;
        const unsigned short* pr = pq + (size_t)sv * 256 + fs;
        const unsigned short* qr = pq + (size_t)dev.x * 256 + 128 + fs;
#pragma unroll
        for (int j = 0; j < 4; ++j) {
            uint4 a = *(const uint4*)(pr + j * 8);
            uint4 b = *(const uint4*)(qr + j * 8);
            uint4 r = make_uint4(pk_add_relu(a.x, b.x), pk_add_relu(a.y, b.y),
                                 pk_add_relu(a.z, b.z), pk_add_relu(a.w, b.w));
            *(uint4*)&E0s[ei][((cb * 4 + j) ^ (ei & 7)) * 8] = r;
        }
    }
    __syncthreads();                 // single barrier

    // phase 2: fp16 MFMA. wave wv: edges [16wv,16wv+16) x 64 outs.
    const int wv = t >> 6, l = t & 63, lq = l >> 4, lm = l & 15;
    frag_cd acc[4];
#pragma unroll
    for (int tb = 0; tb < 4; ++tb) acc[tb] = (frag_cd){0.f, 0.f, 0.f, 0.f};
    const int erow = wv * 16 + lm;
#pragma unroll
    for (int kb = 0; kb < 4; ++kb) {
        const int ca = kb * 4 + lq;
        frag_h af = *(const frag_h*)&E0s[erow][(ca ^ (erow & 7)) * 8];
#pragma unroll
        for (int tb = 0; tb < 4; ++tb) {
            const int rw = tb * 16 + lm;
            frag_h bf = *(const frag_h*)&W1s[rw][(ca ^ (rw & 7)) * 8];
            acc[tb] = __builtin_amdgcn_mfma_f32_16x16x32_f16(af, bf, acc[tb], 0, 0, 0);
        }
    }

    // phase 3: in-register MLP2 (b1/W2 direct from global, L2-resident)
    float b1v[4], w20[4], w21[4];
#pragma unroll
    for (int tb = 0; tb < 4; ++tb) {
        int o = tb * 16 + lm;
        b1v[tb] = b1[o];
        w20[tb] = W2[o * 2];
        w21[tb] = W2[o * 2 + 1];
    }
    const float bo0 = b2[0], bo1 = b2[1];
#pragma unroll
    for (int r = 0; r < 4; ++r) {
        float s0 = 0.f, s1 = 0.f;
#pragma unroll
        for (int tb = 0; tb < 4; ++tb) {
            float e1 = fmaxf(acc[tb][r] + b1v[tb], 0.f);
            s0 += e1 * w20[tb];
            s1 += e1 * w21[tb];
        }
#pragma unroll
        for (int m = 1; m < 16; m <<= 1) {   // reduce over lm
            s0 += __shfl_xor(s0, m, 16);
            s1 += __shfl_xor(s1, m, 16);
        }
        if (lm == 0) {
            int e = wv * 16 + lq * 4 + r;    // 0..127
            *(float2*)&out[(size_t)ee[e] * 2] = make_float2(s0 + bo0, s1 + bo1);
        }
    }
}

// ---------------------------------------------------------------------------
extern "C" void kernel_launch(void* const* d_in, const int* in_sizes, int n_in,
                              void* d_out, int out_size, void* d_ws, size_t ws_size,
                              hipStream_t stream)
{
    const float* x    = (const float*)d_in[0];
    const int*   esrc = (const int*)  d_in[1];
    const int*   edst = (const int*)  d_in[2];
    const float* Wemb  = (const float*)d_in[5];
    const float* bemb  = (const float*)d_in[6];
    const float* Wconv = (const float*)d_in[7];
    const float* bconv = (const float*)d_in[8];
    const float* Wm0   = (const float*)d_in[9];
    const float* bm0   = (const float*)d_in[10];
    const float* Wm1   = (const float*)d_in[11];
    const float* bm1   = (const float*)d_in[12];
    const float* Wm2   = (const float*)d_in[13];
    const float* bm2   = (const float*)d_in[14];
    float* out = (float*)d_out;

    char* ws = (char*)d_ws;
    size_t off = 0;
    auto alloc = [&](size_t bytes) -> void* {
        void* p = ws + off;
        off = (off + bytes + 255) & ~(size_t)255;
        return p;
    };
    unsigned short* h0bf = (unsigned short*)alloc((size_t)NN * 128 * 2);
    unsigned short* h1bf = (unsigned short*)alloc((size_t)NN * 128 * 2);
    unsigned short* cbf  = (unsigned short*)alloc((size_t)NN * 128 * 2);
    unsigned short* pqb  = (unsigned short*)alloc((size_t)NN * 256 * 2);
    unsigned short* xbf  = (unsigned short*)alloc((size_t)NN * 64 * 2);
    unsigned short* Wct   = (unsigned short*)alloc(4 * 128 * 256 * 2);
    unsigned short* Wefft = (unsigned short*)alloc(256 * 128 * 2);
    float*          beff  = (float*)alloc(256 * 4);
    unsigned short* W1tg  = (unsigned short*)alloc(64 * 128 * 2);
    unsigned short* Wembt = (unsigned short*)alloc(128 * 64 * 2);
    int*   deg  = (int*)alloc((size_t)NN * 4);
    int*   rp   = (int*)alloc((size_t)(NN + 1) * 4);
    float* invd = (float*)alloc((size_t)NN * 4);
    int*   bsum = (int*)alloc(512);
    int*   ofs  = (int*)alloc((size_t)NE * 4);
    int*   srt  = (int*)alloc((size_t)NE * 4);
    int2*  de   = (int2*)alloc((size_t)NE * 8);
    (void)ws_size; (void)in_sizes; (void)n_in; (void)out_size;

    hipMemsetAsync(deg, 0, (size_t)NN * 4, stream);

    // cast x -> bf16; weight prep
    cast_k<<<(NN * 64 / 8 + 255) / 256, 256, 0, stream>>>(x, xbf, NN * 64 / 8);
    prep_k<<<(180480 + 255) / 256, 256, 0, stream>>>(
        Wconv, Wm0, bm0, Wm1, Wemb, Wct, Wefft, beff, W1tg, Wembt);

    // CSR build: deg (+per-edge slot), scan, atomic-free fill
    deg_k  <<<(NE + 255) / 256, 256, 0, stream>>>(edst, deg, ofs);
    scan1_k<<<(NN + 511) / 512, 512, 0, stream>>>(deg, rp, bsum);
    scan2_k<<<1, 128, 0, stream>>>(bsum, (NN + 511) / 512);
    scan3_k<<<(NN + 511) / 512, 512, 0, stream>>>(rp, bsum, deg, invd);
    fill_k <<<(NE + 255) / 256, 256, 0, stream>>>(esrc, edst, rp, ofs, srt, de);

    // h0 = bf16(x @ Wemb + bemb) via MFMA
    mfma_gemm_k<EPI_PQBF><<<dim3((NN + 63) / 64, 1), 256, 0, stream>>>(
        xbf, nullptr, 64, 1 << 30, Wembt, bemb, h0bf, 128, nullptr, NN, 64);

    // 4 SAGE layers (MFMA, bf16 residual)
    unsigned short* hcbf = h0bf; unsigned short* hnbf = h1bf;
    for (int l = 0; l < 4; ++l) {
        agg_k<<<(NN + 3) / 4, 256, 0, stream>>>(hcbf, rp, srt, invd, cbf);
        mfma_gemm_k<EPI_LAYER><<<dim3((NN + 63) / 64, 1), 256, 0, stream>>>(
            hcbf, cbf, 128, 128, Wct + (size_t)l * 128 * 256,
            bconv + (size_t)l * 128, hnbf, 128, hcbf, NN, 256);
        unsigned short* tb = hcbf; hcbf = hnbf; hnbf = tb;
    }
    // after 4 layers: hcbf == h0bf

    // pq = fp16(h @ Weff + beff)  [NN][256]  (fp16 feeds edge pipeline)
    mfma_gemm_k<EPI_PQH><<<dim3((NN + 63) / 64, 2), 256, 0, stream>>>(
        hcbf, nullptr, 128, 1 << 30, Wefft, beff, pqb, 256, nullptr, NN, 128);

    // fused edge readout (CSR order, 128 edges/block, single barrier)
    edge_mlp_k<<<NE / 128, 512, 0, stream>>>(pqb, srt, de, W1tg, bm1, Wm2, bm2, out);
}